// Round 10
// baseline (751.953 us; speedup 1.0000x reference)
//
#include <hip/hip_runtime.h>
#include <hip/hip_bf16.h>

// Problem constants (B=8, S=256, D=64, G=32, E=256, L=4, NH=8, DH=8)
constexpr int kB  = 8;
constexpr int kS  = 256;
constexpr int kD  = 64;
constexpr int kG  = 32;
constexpr int kE  = 256;
constexpr int kNH = 8;
constexpr int kHD = 256;              // DH*G = 8*32
constexpr int kDG = kD * kG;          // 2048
constexpr int kT  = kB * kS;          // 2048 tokens
constexpr int kNC = 1000;

using bf16x8 = __attribute__((ext_vector_type(8))) short;
using f32x4  = __attribute__((ext_vector_type(4))) float;

__device__ __forceinline__ short f2bf(float f) {
    unsigned u = __float_as_uint(f);
    unsigned r = (u + 0x7FFFu + ((u >> 16) & 1u)) >> 16;   // RNE
    return (short)r;
}

__device__ __forceinline__ float tanh_fast(float x) {
    float a = fabsf(x);
    float e = __expf(-2.f * a);
    float t = (1.f - e) / (1.f + e);
    return copysignf(t, x);
}

// ---------------- LN of x_in (layer 0) -> A_T bf16 [t][g][i] ----------------
__global__ __launch_bounds__(256) void lnT_kernel(const float* __restrict__ Xin,
                                                  const float* __restrict__ w,
                                                  const float* __restrict__ b,
                                                  unsigned short* __restrict__ AT) {
    int t = blockIdx.x, tid = threadIdx.x;
    __shared__ float sv[64 * 33];       // padded transpose stage
    __shared__ float r1[256], r2[256];
    const float* xp = Xin + (size_t)t * kDG;
    float s = 0.f, ss = 0.f;
#pragma unroll
    for (int j = 0; j < 8; j++) {
        int jj = tid + j * 256;
        float x = xp[jj];
        sv[(jj >> 5) * 33 + (jj & 31)] = x;
        s += x; ss += x * x;
    }
    r1[tid] = s; r2[tid] = ss; __syncthreads();
    for (int o = 128; o > 0; o >>= 1) {
        if (tid < o) { r1[tid] += r1[tid + o]; r2[tid] += r2[tid + o]; }
        __syncthreads();
    }
    float mean = r1[0] * (1.f / kDG);
    float var  = r2[0] * (1.f / kDG) - mean * mean;
    float rstd = rsqrtf(var + 1e-5f);
    int g = tid >> 3, i0 = (tid & 7) * 8;
    short4 o0, o1;
    short* op = (short*)&o0;
#pragma unroll
    for (int k = 0; k < 8; ++k) {
        int i = i0 + k;
        float v = sv[i * 33 + g];
        short r = f2bf((v - mean) * rstd * w[i * kG + g] + b[i * kG + g]);
        if (k < 4) ((short*)&o0)[k] = r; else ((short*)&o1)[k - 4] = r;
    }
    (void)op;
    *(short4*)&AT[(size_t)t * kDG + g * 64 + i0]     = o0;
    *(short4*)&AT[(size_t)t * kDG + g * 64 + i0 + 4] = o1;
}

// ---------------- fused epilogue: residual + mn + (optional) next LN -------
// Wave holds full token output in acc[4][2] (o = mt*16+quad*4+r, g = nt*16+l16).
// Writes X fp32 and (if do_ln) the next A in bf16 transposed form A_T[t][g][o].
__device__ __forceinline__ void epi_res_mn_ln(
    const f32x4 (&acc)[4][2], const float* __restrict__ bias,
    const float* __restrict__ Xin, float* __restrict__ Xout,
    const float* __restrict__ gamma,
    const float* __restrict__ lnw, const float* __restrict__ lnb,
    unsigned short* __restrict__ ATout, int tok, int l16, int quad, bool do_ln) {
    const size_t tb = (size_t)tok * kDG;
    float xv[4][2][4];
    float s = 0.f, ss = 0.f;
#pragma unroll
    for (int mt = 0; mt < 4; ++mt)
#pragma unroll
        for (int r = 0; r < 4; ++r) {
            int o = mt * 16 + quad * 4 + r;
            float vv[2]; float sq = 0.f;
#pragma unroll
            for (int nt = 0; nt < 2; ++nt) {
                int g = nt * 16 + l16;
                float h = acc[mt][nt][r] + bias[o * kG + g];
                float v = Xin[tb + o * kG + g] + gamma[o * kG + g] * h;
                vv[nt] = v; sq = fmaf(v, v, sq);
            }
#pragma unroll
            for (int off = 1; off < 16; off <<= 1) sq += __shfl_xor(sq, off, 64);
            float rn = 1.f / (sqrtf(sq) + 1e-6f);
#pragma unroll
            for (int nt = 0; nt < 2; ++nt) {
                int g = nt * 16 + l16;
                float x = vv[nt] * rn;
                xv[mt][nt][r] = x;
                Xout[tb + o * kG + g] = x;
                s += x; ss = fmaf(x, x, ss);
            }
        }
    if (!do_ln) return;
#pragma unroll
    for (int off = 1; off < 64; off <<= 1) {
        s += __shfl_xor(s, off, 64); ss += __shfl_xor(ss, off, 64);
    }
    float mean = s * (1.f / kDG);
    float var  = ss * (1.f / kDG) - mean * mean;
    float rstd = rsqrtf(var + 1e-5f);
#pragma unroll
    for (int mt = 0; mt < 4; ++mt)
#pragma unroll
        for (int nt = 0; nt < 2; ++nt) {
            int g = nt * 16 + l16;
            short4 s4;
#pragma unroll
            for (int r = 0; r < 4; ++r) {
                int o = mt * 16 + quad * 4 + r;
                ((short*)&s4)[r] = f2bf((xv[mt][nt][r] - mean) * rstd * lnw[o * kG + g] + lnb[o * kG + g]);
            }
            *(short4*)&ATout[tb + g * 64 + mt * 16 + quad * 4] = s4;
        }
}

// ---------------- scalar fp32 versor_linear, TRANSPOSED output --------------
// Kept fp32 (scan leaves are error-sensitive).  Writes DT[b][d][s][g].
__global__ __launch_bounds__(256) void vlinT_kernel(const float* __restrict__ X,
                                                    const float* __restrict__ W,
                                                    const float* __restrict__ bias,
                                                    float* __restrict__ OutT) {
    __shared__ float sx[kDG];      // 8 KB
    __shared__ float sw[kD * kD];  // 16 KB
    int t = blockIdx.x, tid = threadIdx.x;
    const float* xp = X + (size_t)t * kDG;
    for (int j = tid; j < kDG; j += 256) sx[j] = xp[j];
    for (int j = tid; j < kD * kD; j += 256) sw[j] = W[j];
    __syncthreads();
    int g = tid & 31, ob = tid >> 5;
    int b = t >> 8, s = t & 255;
    float* op = OutT + ((size_t)b * kD * kS + s) * kG;
    for (int o = ob; o < kD; o += 8) {
        float acc = bias[o * kG + g];
        const float* wr = sw + o * kD;
#pragma unroll
        for (int i = 0; i < kD; i++) acc += wr[i] * sx[i * kG + g];
        op[(size_t)o * kS * kG + g] = acc;
    }
}

// ---------------- MLP1 GEMM (M=256, tanh, bf16 [t][g][e] out) --------------
// B-fragments load directly from global A_T bf16 (no staging transpose).
__global__ __launch_bounds__(256, 2) void mlp1_kernel(
    const unsigned short* __restrict__ AT, const float* __restrict__ W,
    const float* __restrict__ bias, unsigned short* __restrict__ outH) {
    constexpr int M = 256;
    constexpr int WS = 64 + 8;
    __shared__ short sW[M * WS];

    const int tid = threadIdx.x, wave = tid >> 6, lane = tid & 63;
    const int l16 = lane & 15, quad = lane >> 4;
    const int tok = blockIdx.x * 4 + wave;

    for (int j = tid * 4; j < M * 64; j += 1024) {
        const float4 w4 = *(const float4*)(W + j);
        int o = j >> 6, i = j & 63;
        *(short4*)&sW[o * WS + i] = make_short4(f2bf(w4.x), f2bf(w4.y), f2bf(w4.z), f2bf(w4.w));
    }
    bf16x8 bfr[2][2];
    {
        const unsigned short* ap = AT + (size_t)tok * kDG;
#pragma unroll
        for (int c = 0; c < 2; ++c)
#pragma unroll
            for (int nt = 0; nt < 2; ++nt)
                bfr[c][nt] = *(const bf16x8*)(ap + (nt * 16 + l16) * 64 + c * 32 + quad * 8);
    }
    __syncthreads();

    f32x4 acc[16][2];
#pragma unroll
    for (int mt = 0; mt < 16; ++mt)
#pragma unroll
        for (int nt = 0; nt < 2; ++nt) acc[mt][nt] = (f32x4){0.f, 0.f, 0.f, 0.f};

#pragma unroll
    for (int mt = 0; mt < 16; ++mt)
#pragma unroll
        for (int c = 0; c < 2; ++c) {
            bf16x8 afr = *(const bf16x8*)&sW[(mt * 16 + l16) * WS + c * 32 + quad * 8];
#pragma unroll
            for (int nt = 0; nt < 2; ++nt)
                acc[mt][nt] = __builtin_amdgcn_mfma_f32_16x16x32_bf16(afr, bfr[c][nt], acc[mt][nt], 0, 0, 0);
        }

    unsigned short* op = outH + (size_t)tok * M * kG;   // [t][g][M]
#pragma unroll
    for (int mt = 0; mt < 16; ++mt)
#pragma unroll
        for (int nt = 0; nt < 2; ++nt) {
            int g = nt * 16 + l16;
            int e0 = mt * 16 + quad * 4;
            short4 s4;
            s4.x = f2bf(tanh_fast(acc[mt][nt][0] + bias[(e0 + 0) * kG + g]));
            s4.y = f2bf(tanh_fast(acc[mt][nt][1] + bias[(e0 + 1) * kG + g]));
            s4.z = f2bf(tanh_fast(acc[mt][nt][2] + bias[(e0 + 2) * kG + g]));
            s4.w = f2bf(tanh_fast(acc[mt][nt][3] + bias[(e0 + 3) * kG + g]));
            *(short4*)&op[g * M + e0] = s4;
        }
}

// ---------------- Wo GEMM with fused residual+mn+LN2 epilogue ---------------
// Input = attention output in A_T bf16; B-frags direct from global.
__global__ __launch_bounds__(256, 2) void gemmWo_fused_kernel(
    const unsigned short* __restrict__ AT, const float* __restrict__ W,
    const float* __restrict__ bias,
    const float* __restrict__ Xin, const float* __restrict__ gamma,
    const float* __restrict__ lnw, const float* __restrict__ lnb,
    float* __restrict__ Xout, unsigned short* __restrict__ ATout) {
    constexpr int WS = 64 + 8;
    __shared__ short sW[64 * WS];

    const int tid = threadIdx.x, wave = tid >> 6, lane = tid & 63;
    const int l16 = lane & 15, quad = lane >> 4;
    const int tok = blockIdx.x * 4 + wave;

    for (int j = tid * 4; j < 64 * 64; j += 1024) {
        const float4 w4 = *(const float4*)(W + j);
        int o = j >> 6, i = j & 63;
        *(short4*)&sW[o * WS + i] = make_short4(f2bf(w4.x), f2bf(w4.y), f2bf(w4.z), f2bf(w4.w));
    }
    bf16x8 bfr[2][2];
    {
        const unsigned short* ap = AT + (size_t)tok * kDG;
#pragma unroll
        for (int c = 0; c < 2; ++c)
#pragma unroll
            for (int nt = 0; nt < 2; ++nt)
                bfr[c][nt] = *(const bf16x8*)(ap + (nt * 16 + l16) * 64 + c * 32 + quad * 8);
    }
    __syncthreads();

    f32x4 acc[4][2];
#pragma unroll
    for (int mt = 0; mt < 4; ++mt)
#pragma unroll
        for (int nt = 0; nt < 2; ++nt) acc[mt][nt] = (f32x4){0.f, 0.f, 0.f, 0.f};

#pragma unroll
    for (int mt = 0; mt < 4; ++mt)
#pragma unroll
        for (int c = 0; c < 2; ++c) {
            bf16x8 afr = *(const bf16x8*)&sW[(mt * 16 + l16) * WS + c * 32 + quad * 8];
#pragma unroll
            for (int nt = 0; nt < 2; ++nt)
                acc[mt][nt] = __builtin_amdgcn_mfma_f32_16x16x32_bf16(afr, bfr[c][nt], acc[mt][nt], 0, 0, 0);
        }

    epi_res_mn_ln(acc, bias, Xin, Xout, gamma, lnw, lnb, ATout, tok, l16, quad, true);
}

// ---------------- fused Q/K/V GEMM (A_T input, bf16 outputs) ----------------
__global__ __launch_bounds__(256, 2) void gemm_qkv_kernel(
    const unsigned short* __restrict__ AT,
    const float* __restrict__ Wq, const float* __restrict__ Wk, const float* __restrict__ Wv,
    const float* __restrict__ bq, const float* __restrict__ bk, const float* __restrict__ bv,
    unsigned short* __restrict__ Q, unsigned short* __restrict__ K, unsigned short* __restrict__ V) {
    constexpr int WS = 64 + 8;
    __shared__ short sW[3 * 64 * WS];

    const int tid = threadIdx.x, wave = tid >> 6, lane = tid & 63;
    const int l16 = lane & 15, quad = lane >> 4;
    const int tok = blockIdx.x * 4 + wave;

    const float* Wp[3] = {Wq, Wk, Wv};
#pragma unroll
    for (int w = 0; w < 3; ++w)
        for (int j = tid * 4; j < 64 * 64; j += 1024) {
            const float4 w4 = *(const float4*)(Wp[w] + j);
            int o = j >> 6, i = j & 63;
            *(short4*)&sW[w * 64 * WS + o * WS + i] =
                make_short4(f2bf(w4.x), f2bf(w4.y), f2bf(w4.z), f2bf(w4.w));
        }
    bf16x8 bfr[2][2];
    {
        const unsigned short* ap = AT + (size_t)tok * kDG;
#pragma unroll
        for (int c = 0; c < 2; ++c)
#pragma unroll
            for (int nt = 0; nt < 2; ++nt)
                bfr[c][nt] = *(const bf16x8*)(ap + (nt * 16 + l16) * 64 + c * 32 + quad * 8);
    }
    __syncthreads();

    f32x4 acc[3][4][2];
#pragma unroll
    for (int w = 0; w < 3; ++w)
#pragma unroll
        for (int mt = 0; mt < 4; ++mt)
#pragma unroll
            for (int nt = 0; nt < 2; ++nt) acc[w][mt][nt] = (f32x4){0.f, 0.f, 0.f, 0.f};

#pragma unroll
    for (int w = 0; w < 3; ++w)
#pragma unroll
        for (int mt = 0; mt < 4; ++mt)
#pragma unroll
            for (int c = 0; c < 2; ++c) {
                bf16x8 afr = *(const bf16x8*)&sW[w * 64 * WS + (mt * 16 + l16) * WS + c * 32 + quad * 8];
#pragma unroll
                for (int nt = 0; nt < 2; ++nt)
                    acc[w][mt][nt] = __builtin_amdgcn_mfma_f32_16x16x32_bf16(afr, bfr[c][nt], acc[w][mt][nt], 0, 0, 0);
            }

    unsigned short* Op[3] = {Q, K, V};
    const float* Bp[3] = {bq, bk, bv};
#pragma unroll
    for (int w = 0; w < 3; ++w) {
        unsigned short* op = Op[w] + (size_t)tok * kDG;
#pragma unroll
        for (int mt = 0; mt < 4; ++mt)
#pragma unroll
            for (int nt = 0; nt < 2; ++nt) {
                int g = nt * 16 + l16;
#pragma unroll
                for (int r = 0; r < 4; ++r) {
                    int o = mt * 16 + quad * 4 + r;
                    op[o * kG + g] = (unsigned short)f2bf(acc[w][mt][nt][r] + Bp[w][o * kG + g]);
                }
            }
    }
}

// ---------------- MLP2 GEMM with fused residual+mn+(LN1 next) epilogue -----
template<bool DO_LN>
__global__ __launch_bounds__(256, 2) void mlp2_fused_kernel(
    const unsigned short* __restrict__ Mb,  // [t][32][256] bf16
    const float* __restrict__ W2, const float* __restrict__ b2,
    float* __restrict__ X, const float* __restrict__ gamma,
    const float* __restrict__ lnw, const float* __restrict__ lnb,
    unsigned short* __restrict__ ATout) {
    constexpr int WS = 256 + 8;
    __shared__ short sW[64 * WS];
    const int tid = threadIdx.x, wave = tid >> 6, lane = tid & 63;
    const int l16 = lane & 15, quad = lane >> 4;
    const int tok = blockIdx.x * 4 + wave;

    for (int j = tid * 4; j < 64 * 256; j += 1024) {
        const float4 w4 = *(const float4*)(W2 + j);
        int o = j >> 8, i = j & 255;
        *(short4*)&sW[o * WS + i] = make_short4(f2bf(w4.x), f2bf(w4.y), f2bf(w4.z), f2bf(w4.w));
    }
    __syncthreads();

    f32x4 acc[4][2];
#pragma unroll
    for (int mt = 0; mt < 4; ++mt)
#pragma unroll
        for (int nt = 0; nt < 2; ++nt) acc[mt][nt] = (f32x4){0.f, 0.f, 0.f, 0.f};

    const unsigned short* mp = Mb + (size_t)tok * kG * kE;
#pragma unroll
    for (int c = 0; c < 8; ++c) {
        bf16x8 bfr[2];
#pragma unroll
        for (int nt = 0; nt < 2; ++nt)
            bfr[nt] = *(const bf16x8*)&mp[(nt * 16 + l16) * kE + c * 32 + quad * 8];
#pragma unroll
        for (int mt = 0; mt < 4; ++mt) {
            bf16x8 afr = *(const bf16x8*)&sW[(mt * 16 + l16) * WS + c * 32 + quad * 8];
#pragma unroll
            for (int nt = 0; nt < 2; ++nt)
                acc[mt][nt] = __builtin_amdgcn_mfma_f32_16x16x32_bf16(afr, bfr[nt], acc[mt][nt], 0, 0, 0);
        }
    }

    epi_res_mn_ln(acc, b2, X, X, gamma, lnw, lnb, ATout, tok, l16, quad, DO_LN);
}

// ---------------- MFMA flash-style attention v3 -----------------------------
// Q A-frags and K B-frags load DIRECTLY from global (bf16, MFMA-interleaved);
// LDS only for P, V-transpose, and the O->A_T bounce.  Output = A_T bf16.
constexpr int QSTR = 264;
constexpr int VSTR = 40;

__global__ __launch_bounds__(256) void attn_mfma_kernel(const unsigned short* __restrict__ Q,
                                                        const unsigned short* __restrict__ K,
                                                        const unsigned short* __restrict__ V,
                                                        unsigned short* __restrict__ AT) {
    __shared__ short sP[64 * QSTR];      // P (bf16), later O bounce
    __shared__ short sVT[256 * VSTR];    // V^T tiles

    const int qt = blockIdx.x, h = blockIdx.y, b = blockIdx.z;
    const int tid = threadIdx.x;
    const int wave = tid >> 6, lane = tid & 63;
    const int l16 = lane & 15, quad = lane >> 4;

    const size_t bh = (size_t)b * kS * kDG + (size_t)h * kHD;

    // Q A-frags: direct global loads (per-lane q row = qt*64 + wave*16 + l16)
    bf16x8 afrag[8];
    {
        const unsigned short* qp = Q + bh + (size_t)(qt * 64 + wave * 16 + l16) * kDG;
#pragma unroll
        for (int c = 0; c < 8; ++c)
            afrag[c] = *(const bf16x8*)(qp + c * 32 + quad * 8);
    }

    // scores: 16 n-tiles of 16 keys, K B-frags direct from global
    f32x4 acc[16];
#pragma unroll
    for (int i = 0; i < 16; ++i) acc[i] = (f32x4){0.f, 0.f, 0.f, 0.f};
#pragma unroll 2
    for (int n = 0; n < 16; ++n) {
        const unsigned short* kp = K + bh + (size_t)(n * 16 + l16) * kDG;
        f32x4 a = acc[n];
#pragma unroll
        for (int c = 0; c < 8; ++c) {
            bf16x8 bfrag = *(const bf16x8*)(kp + c * 32 + quad * 8);
            a = __builtin_amdgcn_mfma_f32_16x16x32_bf16(afrag[c], bfrag, a, 0, 0, 0);
        }
        acc[n] = a;
    }

    // softmax over 256 keys (rows = quad*4 + r)
    float inv[4];
#pragma unroll
    for (int r = 0; r < 4; ++r) {
        float m = -1e30f;
#pragma unroll
        for (int t = 0; t < 16; ++t) m = fmaxf(m, acc[t][r]);
#pragma unroll
        for (int off = 1; off < 16; off <<= 1) m = fmaxf(m, __shfl_xor(m, off, 16));
        float s = 0.f;
#pragma unroll
        for (int t = 0; t < 16; ++t) {
            float p = __expf((acc[t][r] - m) * 0.0625f);
            acc[t][r] = p; s += p;
        }
#pragma unroll
        for (int off = 1; off < 16; off <<= 1) s += __shfl_xor(s, off, 16);
        inv[r] = 1.f / s;
    }

    // P (bf16) into sP — each wave writes only its own 16 rows
#pragma unroll
    for (int t = 0; t < 16; ++t)
#pragma unroll
        for (int r = 0; r < 4; ++r)
            sP[(wave * 16 + quad * 4 + r) * QSTR + t * 16 + l16] = f2bf(acc[t][r]);

    // PV
    f32x4 oacc[16];
#pragma unroll
    for (int i = 0; i < 16; ++i) oacc[i] = (f32x4){0.f, 0.f, 0.f, 0.f};

    for (int vt = 0; vt < 8; ++vt) {
        __syncthreads();
        {
            int kb = tid >> 5;
#pragma unroll
            for (int it = 0; it < 2; ++it) {
                int db = (tid & 31) + it * 32;
                short4 vr[4];
#pragma unroll
                for (int r = 0; r < 4; ++r)
                    vr[r] = *(const short4*)(V + bh + (size_t)(vt * 32 + kb * 4 + r) * kDG + db * 4);
#pragma unroll
                for (int i = 0; i < 4; ++i) {
                    short4 p = make_short4((&vr[0].x)[i], (&vr[1].x)[i],
                                           (&vr[2].x)[i], (&vr[3].x)[i]);
                    *(short4*)&sVT[(db * 4 + i) * VSTR + kb * 4] = p;
                }
            }
        }
        __syncthreads();
        bf16x8 pfrag = *(const bf16x8*)&sP[(wave * 16 + l16) * QSTR + vt * 32 + quad * 8];
#pragma unroll
        for (int dt = 0; dt < 16; ++dt) {
            bf16x8 vfrag = *(const bf16x8*)&sVT[(dt * 16 + l16) * VSTR + quad * 8];
            oacc[dt] = __builtin_amdgcn_mfma_f32_16x16x32_bf16(pfrag, vfrag, oacc[dt], 0, 0, 0);
        }
    }

    // O -> LDS bounce in [q][g*8 + i_local] layout (own rows), then A_T write
#pragma unroll
    for (int dt = 0; dt < 16; ++dt)
#pragma unroll
        for (int r = 0; r < 4; ++r) {
            int hd = dt * 16 + l16;
            int g = hd & 31, il = hd >> 5;
            sP[(wave * 16 + quad * 4 + r) * QSTR + g * 8 + il] = f2bf(oacc[dt][r] * inv[r]);
        }
    __syncthreads();
#pragma unroll
    for (int it = 0; it < 8; ++it) {
        int idx = it * 256 + tid;
        int q = idx >> 5, g = idx & 31;
        size_t dst = ((size_t)(b * kS + qt * 64 + q)) * kDG + g * 64 + h * 8;
        *(bf16x8*)&AT[dst] = *(const bf16x8*)&sP[q * QSTR + g * 8];
    }
}

// ---------------- in-thread geometric product with compile-time signs -------
constexpr int pc_ce(unsigned v) { int c = 0; while (v) { c += v & 1; v >>= 1; } return c; }
constexpr unsigned gp_mask_ce(int a) {
    unsigned m = 0;
    for (int c = 0; c < 32; ++c) {
        int b = a ^ c;
        int s = (a & b) >> 4;                       // SIG[4] = -1 metric term
        for (int t = a >> 1; t; t >>= 1) s += pc_ce(t & b);
        if (s & 1) m |= (1u << c);
    }
    return m;
}

template<int A>
__device__ __forceinline__ void gp_term(const float* x, const float* y, float* acc) {
    constexpr unsigned m = gp_mask_ce(A);
    const float xa = x[A], nxa = -xa;
#pragma unroll
    for (int c = 0; c < 32; ++c)
        acc[c] = fmaf(((m >> c) & 1u) ? nxa : xa, y[A ^ c], acc[c]);
}

__device__ __forceinline__ void gp_mn_t(const float* x, const float* y, float* out) {
    float acc[32];
#pragma unroll
    for (int c = 0; c < 32; ++c) acc[c] = 0.f;
    gp_term<0>(x, y, acc);  gp_term<1>(x, y, acc);  gp_term<2>(x, y, acc);  gp_term<3>(x, y, acc);
    gp_term<4>(x, y, acc);  gp_term<5>(x, y, acc);  gp_term<6>(x, y, acc);  gp_term<7>(x, y, acc);
    gp_term<8>(x, y, acc);  gp_term<9>(x, y, acc);  gp_term<10>(x, y, acc); gp_term<11>(x, y, acc);
    gp_term<12>(x, y, acc); gp_term<13>(x, y, acc); gp_term<14>(x, y, acc); gp_term<15>(x, y, acc);
    gp_term<16>(x, y, acc); gp_term<17>(x, y, acc); gp_term<18>(x, y, acc); gp_term<19>(x, y, acc);
    gp_term<20>(x, y, acc); gp_term<21>(x, y, acc); gp_term<22>(x, y, acc); gp_term<23>(x, y, acc);
    gp_term<24>(x, y, acc); gp_term<25>(x, y, acc); gp_term<26>(x, y, acc); gp_term<27>(x, y, acc);
    gp_term<28>(x, y, acc); gp_term<29>(x, y, acc); gp_term<30>(x, y, acc); gp_term<31>(x, y, acc);
    float ss = 0.f;
#pragma unroll
    for (int c = 0; c < 32; ++c) ss = fmaf(acc[c], acc[c], ss);
    float r = 1.f / (sqrtf(ss) + 1e-6f);
#pragma unroll
    for (int c = 0; c < 32; ++c) out[c] = acc[c] * r;
}

__device__ __forceinline__ void leaf_load(const float* base, float* v) {
#pragma unroll
    for (int i = 0; i < 8; ++i) {
        const float4 f = *(const float4*)(base + i * 4);
        v[i * 4 + 0] = 0.5f * f.x; v[i * 4 + 1] = 0.5f * f.y;
        v[i * 4 + 2] = 0.5f * f.z; v[i * 4 + 3] = 0.5f * f.w;
    }
    v[0] += 1.f;
    float ss = 0.f;
#pragma unroll
    for (int c = 0; c < 32; ++c) ss = fmaf(v[c], v[c], ss);
    float r = 1.f / (sqrtf(ss) + 1e-6f);
#pragma unroll
    for (int c = 0; c < 32; ++c) v[c] *= r;
}

// ---------------- scan: wave per sequence, rotor per thread -----------------
__global__ __launch_bounds__(256) void scanreg_kernel(const float* __restrict__ DT,
                                                      float* __restrict__ pooled) {
    const int wave = threadIdx.x >> 6, lane = threadIdx.x & 63;
    const int seq = blockIdx.x * 4 + wave;               // b*64 + d
    const float* base = DT + ((size_t)seq * kS + lane * 4) * kG;

    float R[32], Y[32], P[32], Xa[32], Yb[32];

    leaf_load(base, R);
    for (int j = 1; j < 4; ++j) {
        leaf_load(base + j * kG, Y);
        gp_mn_t(Y, R, R);                                // later ∘ earlier
    }

    for (int step = 1; step < 64; step <<= 1) {
        const bool up = lane & step;
#pragma unroll
        for (int c = 0; c < 32; ++c) P[c] = __shfl_xor(R[c], step, 64);
#pragma unroll
        for (int c = 0; c < 32; ++c) {
            Xa[c] = up ? R[c] : P[c];
            Yb[c] = up ? P[c] : R[c];
        }
        gp_mn_t(Xa, Yb, R);
    }

    if (lane == 0) {
        float* op = pooled + (size_t)seq * kG;
#pragma unroll
        for (int i = 0; i < 8; ++i)
            *(float4*)(op + i * 4) = make_float4(R[i * 4], R[i * 4 + 1], R[i * 4 + 2], R[i * 4 + 3]);
    }
}

// ---------------- classifier: wave per class, pooled staged in LDS ----------
__global__ __launch_bounds__(256) void cls2_kernel(const float* __restrict__ P,
                                                   const float* __restrict__ Wc,
                                                   const float* __restrict__ bc,
                                                   float* __restrict__ out) {
    __shared__ float sp[kB * kDG];   // 64 KB
    const int tid = threadIdx.x, wave = tid >> 6, lane = tid & 63;
    for (int j = tid * 4; j < kB * kDG; j += 1024)
        *(float4*)&sp[j] = *(const float4*)(P + j);
    __syncthreads();

    const int c = blockIdx.x * 4 + wave;
    const float* w = Wc + (size_t)c * kDG;
    float acc[kB];
#pragma unroll
    for (int b = 0; b < kB; ++b) acc[b] = 0.f;
#pragma unroll
    for (int cc = 0; cc < 8; ++cc) {
        const float4 w4 = *(const float4*)(w + cc * 256 + lane * 4);
#pragma unroll
        for (int b = 0; b < kB; ++b) {
            const float4 p4 = *(const float4*)&sp[b * kDG + cc * 256 + lane * 4];
            acc[b] += w4.x * p4.x + w4.y * p4.y + w4.z * p4.z + w4.w * p4.w;
        }
    }
#pragma unroll
    for (int b = 0; b < kB; ++b)
#pragma unroll
        for (int off = 32; off > 0; off >>= 1) acc[b] += __shfl_xor(acc[b], off, 64);
    if (lane == 0) {
        float bias = bc[c];
#pragma unroll
        for (int b = 0; b < kB; ++b) out[b * kNC + c] = acc[b] + bias;
    }
}

extern "C" void kernel_launch(void* const* d_in, const int* in_sizes, int n_in,
                              void* d_out, int out_size, void* d_ws, size_t ws_size,
                              hipStream_t stream) {
    const float* x_in = (const float*)d_in[0];
    const float* Wq   = (const float*)d_in[1];
    const float* bq   = (const float*)d_in[2];
    const float* Wk   = (const float*)d_in[3];
    const float* bk   = (const float*)d_in[4];
    const float* Wv   = (const float*)d_in[5];
    const float* bv   = (const float*)d_in[6];
    const float* Wo   = (const float*)d_in[7];
    const float* bo   = (const float*)d_in[8];
    const float* ln1w = (const float*)d_in[9];
    const float* ln1b = (const float*)d_in[10];
    const float* ln2w = (const float*)d_in[11];
    const float* ln2b = (const float*)d_in[12];
    const float* gm1  = (const float*)d_in[13];
    const float* gm2  = (const float*)d_in[14];
    const float* W1   = (const float*)d_in[15];
    const float* b1   = (const float*)d_in[16];
    const float* W2   = (const float*)d_in[17];
    const float* b2   = (const float*)d_in[18];
    const float* Wr   = (const float*)d_in[19];
    const float* br   = (const float*)d_in[20];
    const float* Wc   = (const float*)d_in[21];
    const float* bc   = (const float*)d_in[22];

    const size_t NEL = (size_t)kT * kDG;
    float* F  = (float*)d_ws;
    float* X  = F;                                   // fp32 residual
    unsigned short* Ah = (unsigned short*)(F + NEL); // bf16 A_T (8 MB of region)
    float* DT = F + NEL;                             // fp32 delta^T (same region, after layers)
    unsigned short* Qh = (unsigned short*)(F + 2 * NEL);
    unsigned short* Kh = (unsigned short*)(F + 3 * NEL);
    unsigned short* Vh = (unsigned short*)(F + 4 * NEL);
    unsigned short* Mb = (unsigned short*)(F + 3 * NEL);  // bf16 [t][32][256], spans Kb+Vb
    float* pooled = F + 2 * NEL;                     // Qb region free at scan time

    lnT_kernel<<<kT, 256, 0, stream>>>(x_in, ln1w, ln1b, Ah);

    for (int l = 0; l < 4; l++) {
        gemm_qkv_kernel<<<kT / 4, 256, 0, stream>>>(Ah,
            Wq + l * kD * kD, Wk + l * kD * kD, Wv + l * kD * kD,
            bq + l * kDG, bk + l * kDG, bv + l * kDG, Qh, Kh, Vh);
        attn_mfma_kernel<<<dim3(4, kNH, kB), 256, 0, stream>>>(Qh, Kh, Vh, Ah);
        gemmWo_fused_kernel<<<kT / 4, 256, 0, stream>>>(Ah, Wo + l * kD * kD, bo + l * kDG,
            l == 0 ? x_in : X, gm1 + l * kDG, ln2w + l * kDG, ln2b + l * kDG, X, Ah);
        mlp1_kernel<<<kT / 4, 256, 0, stream>>>(Ah, W1 + l * kE * kD, b1 + l * kE * kG, Mb);
        if (l < 3)
            mlp2_fused_kernel<true><<<kT / 4, 256, 0, stream>>>(Mb, W2 + l * kD * kE, b2 + l * kDG,
                X, gm2 + l * kDG, ln1w + (l + 1) * kDG, ln1b + (l + 1) * kDG, Ah);
        else
            mlp2_fused_kernel<false><<<kT / 4, 256, 0, stream>>>(Mb, W2 + l * kD * kE, b2 + l * kDG,
                X, gm2 + l * kDG, nullptr, nullptr, nullptr);
    }

    // delta (fp32, transposed layout) -> register-resident reduction -> classifier
    vlinT_kernel<<<kT, 256, 0, stream>>>(X, Wr, br, DT);
    scanreg_kernel<<<kB * kD / 4, 256, 0, stream>>>(DT, pooled);
    cls2_kernel<<<kNC / 4, 256, 0, stream>>>(pooled, Wc, bc, (float*)d_out);
}

// Round 11
// 657.552 us; speedup vs baseline: 1.1436x; 1.1436x over previous
//
#include <hip/hip_runtime.h>
#include <hip/hip_bf16.h>

// Problem constants (B=8, S=256, D=64, G=32, E=256, L=4, NH=8, DH=8)
constexpr int kB  = 8;
constexpr int kS  = 256;
constexpr int kD  = 64;
constexpr int kG  = 32;
constexpr int kE  = 256;
constexpr int kNH = 8;
constexpr int kHD = 256;              // DH*G = 8*32
constexpr int kDG = kD * kG;          // 2048
constexpr int kT  = kB * kS;          // 2048 tokens
constexpr int kNC = 1000;

using bf16x8 = __attribute__((ext_vector_type(8))) short;
using f32x4  = __attribute__((ext_vector_type(4))) float;

__device__ __forceinline__ short f2bf(float f) {
    unsigned u = __float_as_uint(f);
    unsigned r = (u + 0x7FFFu + ((u >> 16) & 1u)) >> 16;   // RNE
    return (short)r;
}

__device__ __forceinline__ float tanh_fast(float x) {
    float a = fabsf(x);
    float e = __expf(-2.f * a);
    float t = (1.f - e) / (1.f + e);
    return copysignf(t, x);
}

// ---------------- LN of x_in (layer 0) -> A_T bf16 [t][g][i] ----------------
__global__ __launch_bounds__(256) void lnT_kernel(const float* __restrict__ Xin,
                                                  const float* __restrict__ w,
                                                  const float* __restrict__ b,
                                                  unsigned short* __restrict__ AT) {
    int t = blockIdx.x, tid = threadIdx.x;
    __shared__ float sv[64 * 33];       // padded transpose stage
    __shared__ float r1[256], r2[256];
    const float* xp = Xin + (size_t)t * kDG;
    float s = 0.f, ss = 0.f;
#pragma unroll
    for (int j = 0; j < 8; j++) {
        int jj = tid + j * 256;
        float x = xp[jj];
        sv[(jj >> 5) * 33 + (jj & 31)] = x;
        s += x; ss += x * x;
    }
    r1[tid] = s; r2[tid] = ss; __syncthreads();
    for (int o = 128; o > 0; o >>= 1) {
        if (tid < o) { r1[tid] += r1[tid + o]; r2[tid] += r2[tid + o]; }
        __syncthreads();
    }
    float mean = r1[0] * (1.f / kDG);
    float var  = r2[0] * (1.f / kDG) - mean * mean;
    float rstd = rsqrtf(var + 1e-5f);
    int g = tid >> 3, i0 = (tid & 7) * 8;
    short4 o0, o1;
#pragma unroll
    for (int k = 0; k < 8; ++k) {
        int i = i0 + k;
        float v = sv[i * 33 + g];
        short r = f2bf((v - mean) * rstd * w[i * kG + g] + b[i * kG + g]);
        if (k < 4) ((short*)&o0)[k] = r; else ((short*)&o1)[k - 4] = r;
    }
    *(short4*)&AT[(size_t)t * kDG + g * 64 + i0]     = o0;
    *(short4*)&AT[(size_t)t * kDG + g * 64 + i0 + 4] = o1;
}

// ---------------- fused epilogue: residual + mn + (optional) next LN -------
// Wave holds full token output in acc[4][2] (o = mt*16+quad*4+r, g = nt*16+l16).
// Writes X fp32 and (if do_ln) the next A in bf16 transposed form A_T[t][g][o].
__device__ __forceinline__ void epi_res_mn_ln(
    const f32x4 (&acc)[4][2], const float* __restrict__ bias,
    const float* __restrict__ Xin, float* __restrict__ Xout,
    const float* __restrict__ gamma,
    const float* __restrict__ lnw, const float* __restrict__ lnb,
    unsigned short* __restrict__ ATout, int tok, int l16, int quad, bool do_ln) {
    const size_t tb = (size_t)tok * kDG;
    float xv[4][2][4];
    float s = 0.f, ss = 0.f;
#pragma unroll
    for (int mt = 0; mt < 4; ++mt)
#pragma unroll
        for (int r = 0; r < 4; ++r) {
            int o = mt * 16 + quad * 4 + r;
            float vv[2]; float sq = 0.f;
#pragma unroll
            for (int nt = 0; nt < 2; ++nt) {
                int g = nt * 16 + l16;
                float h = acc[mt][nt][r] + bias[o * kG + g];
                float v = Xin[tb + o * kG + g] + gamma[o * kG + g] * h;
                vv[nt] = v; sq = fmaf(v, v, sq);
            }
#pragma unroll
            for (int off = 1; off < 16; off <<= 1) sq += __shfl_xor(sq, off, 64);
            float rn = 1.f / (sqrtf(sq) + 1e-6f);
#pragma unroll
            for (int nt = 0; nt < 2; ++nt) {
                int g = nt * 16 + l16;
                float x = vv[nt] * rn;
                xv[mt][nt][r] = x;
                Xout[tb + o * kG + g] = x;
                s += x; ss = fmaf(x, x, ss);
            }
        }
    if (!do_ln) return;
#pragma unroll
    for (int off = 1; off < 64; off <<= 1) {
        s += __shfl_xor(s, off, 64); ss += __shfl_xor(ss, off, 64);
    }
    float mean = s * (1.f / kDG);
    float var  = ss * (1.f / kDG) - mean * mean;
    float rstd = rsqrtf(var + 1e-5f);
#pragma unroll
    for (int mt = 0; mt < 4; ++mt)
#pragma unroll
        for (int nt = 0; nt < 2; ++nt) {
            int g = nt * 16 + l16;
            short4 s4;
#pragma unroll
            for (int r = 0; r < 4; ++r) {
                int o = mt * 16 + quad * 4 + r;
                ((short*)&s4)[r] = f2bf((xv[mt][nt][r] - mean) * rstd * lnw[o * kG + g] + lnb[o * kG + g]);
            }
            *(short4*)&ATout[tb + g * 64 + mt * 16 + quad * 4] = s4;
        }
}

// ---------------- scalar fp32 versor_linear, TRANSPOSED output --------------
// Kept fp32 (scan leaves are error-sensitive).  Writes DT[b][d][s][g].
__global__ __launch_bounds__(256) void vlinT_kernel(const float* __restrict__ X,
                                                    const float* __restrict__ W,
                                                    const float* __restrict__ bias,
                                                    float* __restrict__ OutT) {
    __shared__ float sx[kDG];      // 8 KB
    __shared__ float sw[kD * kD];  // 16 KB
    int t = blockIdx.x, tid = threadIdx.x;
    const float* xp = X + (size_t)t * kDG;
    for (int j = tid; j < kDG; j += 256) sx[j] = xp[j];
    for (int j = tid; j < kD * kD; j += 256) sw[j] = W[j];
    __syncthreads();
    int g = tid & 31, ob = tid >> 5;
    int b = t >> 8, s = t & 255;
    float* op = OutT + ((size_t)b * kD * kS + s) * kG;
    for (int o = ob; o < kD; o += 8) {
        float acc = bias[o * kG + g];
        const float* wr = sw + o * kD;
#pragma unroll
        for (int i = 0; i < kD; i++) acc += wr[i] * sx[i * kG + g];
        op[(size_t)o * kS * kG + g] = acc;
    }
}

// ---------------- MLP1 GEMM (M=256, tanh, bf16 [t][g][e] out) --------------
// B-fragments load directly from global A_T bf16 (no staging transpose).
__global__ __launch_bounds__(256, 2) void mlp1_kernel(
    const unsigned short* __restrict__ AT, const float* __restrict__ W,
    const float* __restrict__ bias, unsigned short* __restrict__ outH) {
    constexpr int M = 256;
    constexpr int WS = 64 + 8;
    __shared__ short sW[M * WS];

    const int tid = threadIdx.x, wave = tid >> 6, lane = tid & 63;
    const int l16 = lane & 15, quad = lane >> 4;
    const int tok = blockIdx.x * 4 + wave;

    for (int j = tid * 4; j < M * 64; j += 1024) {
        const float4 w4 = *(const float4*)(W + j);
        int o = j >> 6, i = j & 63;
        *(short4*)&sW[o * WS + i] = make_short4(f2bf(w4.x), f2bf(w4.y), f2bf(w4.z), f2bf(w4.w));
    }
    bf16x8 bfr[2][2];
    {
        const unsigned short* ap = AT + (size_t)tok * kDG;
#pragma unroll
        for (int c = 0; c < 2; ++c)
#pragma unroll
            for (int nt = 0; nt < 2; ++nt)
                bfr[c][nt] = *(const bf16x8*)(ap + (nt * 16 + l16) * 64 + c * 32 + quad * 8);
    }
    __syncthreads();

    f32x4 acc[16][2];
#pragma unroll
    for (int mt = 0; mt < 16; ++mt)
#pragma unroll
        for (int nt = 0; nt < 2; ++nt) acc[mt][nt] = (f32x4){0.f, 0.f, 0.f, 0.f};

#pragma unroll
    for (int mt = 0; mt < 16; ++mt)
#pragma unroll
        for (int c = 0; c < 2; ++c) {
            bf16x8 afr = *(const bf16x8*)&sW[(mt * 16 + l16) * WS + c * 32 + quad * 8];
#pragma unroll
            for (int nt = 0; nt < 2; ++nt)
                acc[mt][nt] = __builtin_amdgcn_mfma_f32_16x16x32_bf16(afr, bfr[c][nt], acc[mt][nt], 0, 0, 0);
        }

    unsigned short* op = outH + (size_t)tok * M * kG;   // [t][g][M]
#pragma unroll
    for (int mt = 0; mt < 16; ++mt)
#pragma unroll
        for (int nt = 0; nt < 2; ++nt) {
            int g = nt * 16 + l16;
            int e0 = mt * 16 + quad * 4;
            short4 s4;
            s4.x = f2bf(tanh_fast(acc[mt][nt][0] + bias[(e0 + 0) * kG + g]));
            s4.y = f2bf(tanh_fast(acc[mt][nt][1] + bias[(e0 + 1) * kG + g]));
            s4.z = f2bf(tanh_fast(acc[mt][nt][2] + bias[(e0 + 2) * kG + g]));
            s4.w = f2bf(tanh_fast(acc[mt][nt][3] + bias[(e0 + 3) * kG + g]));
            *(short4*)&op[g * M + e0] = s4;
        }
}

// ---------------- Wo GEMM with fused residual+mn+LN2 epilogue ---------------
__global__ __launch_bounds__(256, 2) void gemmWo_fused_kernel(
    const unsigned short* __restrict__ AT, const float* __restrict__ W,
    const float* __restrict__ bias,
    const float* __restrict__ Xin, const float* __restrict__ gamma,
    const float* __restrict__ lnw, const float* __restrict__ lnb,
    float* __restrict__ Xout, unsigned short* __restrict__ ATout) {
    constexpr int WS = 64 + 8;
    __shared__ short sW[64 * WS];

    const int tid = threadIdx.x, wave = tid >> 6, lane = tid & 63;
    const int l16 = lane & 15, quad = lane >> 4;
    const int tok = blockIdx.x * 4 + wave;

    for (int j = tid * 4; j < 64 * 64; j += 1024) {
        const float4 w4 = *(const float4*)(W + j);
        int o = j >> 6, i = j & 63;
        *(short4*)&sW[o * WS + i] = make_short4(f2bf(w4.x), f2bf(w4.y), f2bf(w4.z), f2bf(w4.w));
    }
    bf16x8 bfr[2][2];
    {
        const unsigned short* ap = AT + (size_t)tok * kDG;
#pragma unroll
        for (int c = 0; c < 2; ++c)
#pragma unroll
            for (int nt = 0; nt < 2; ++nt)
                bfr[c][nt] = *(const bf16x8*)(ap + (nt * 16 + l16) * 64 + c * 32 + quad * 8);
    }
    __syncthreads();

    f32x4 acc[4][2];
#pragma unroll
    for (int mt = 0; mt < 4; ++mt)
#pragma unroll
        for (int nt = 0; nt < 2; ++nt) acc[mt][nt] = (f32x4){0.f, 0.f, 0.f, 0.f};

#pragma unroll
    for (int mt = 0; mt < 4; ++mt)
#pragma unroll
        for (int c = 0; c < 2; ++c) {
            bf16x8 afr = *(const bf16x8*)&sW[(mt * 16 + l16) * WS + c * 32 + quad * 8];
#pragma unroll
            for (int nt = 0; nt < 2; ++nt)
                acc[mt][nt] = __builtin_amdgcn_mfma_f32_16x16x32_bf16(afr, bfr[c][nt], acc[mt][nt], 0, 0, 0);
        }

    epi_res_mn_ln(acc, bias, Xin, Xout, gamma, lnw, lnb, ATout, tok, l16, quad, true);
}

// ---------------- fused Q/K/V GEMM (A_T input, bf16 outputs) ----------------
__global__ __launch_bounds__(256, 2) void gemm_qkv_kernel(
    const unsigned short* __restrict__ AT,
    const float* __restrict__ Wq, const float* __restrict__ Wk, const float* __restrict__ Wv,
    const float* __restrict__ bq, const float* __restrict__ bk, const float* __restrict__ bv,
    unsigned short* __restrict__ Q, unsigned short* __restrict__ K, unsigned short* __restrict__ V) {
    constexpr int WS = 64 + 8;
    __shared__ short sW[3 * 64 * WS];

    const int tid = threadIdx.x, wave = tid >> 6, lane = tid & 63;
    const int l16 = lane & 15, quad = lane >> 4;
    const int tok = blockIdx.x * 4 + wave;

    const float* Wp[3] = {Wq, Wk, Wv};
#pragma unroll
    for (int w = 0; w < 3; ++w)
        for (int j = tid * 4; j < 64 * 64; j += 1024) {
            const float4 w4 = *(const float4*)(Wp[w] + j);
            int o = j >> 6, i = j & 63;
            *(short4*)&sW[w * 64 * WS + o * WS + i] =
                make_short4(f2bf(w4.x), f2bf(w4.y), f2bf(w4.z), f2bf(w4.w));
        }
    bf16x8 bfr[2][2];
    {
        const unsigned short* ap = AT + (size_t)tok * kDG;
#pragma unroll
        for (int c = 0; c < 2; ++c)
#pragma unroll
            for (int nt = 0; nt < 2; ++nt)
                bfr[c][nt] = *(const bf16x8*)(ap + (nt * 16 + l16) * 64 + c * 32 + quad * 8);
    }
    __syncthreads();

    f32x4 acc[3][4][2];
#pragma unroll
    for (int w = 0; w < 3; ++w)
#pragma unroll
        for (int mt = 0; mt < 4; ++mt)
#pragma unroll
            for (int nt = 0; nt < 2; ++nt) acc[w][mt][nt] = (f32x4){0.f, 0.f, 0.f, 0.f};

#pragma unroll
    for (int w = 0; w < 3; ++w)
#pragma unroll
        for (int mt = 0; mt < 4; ++mt)
#pragma unroll
            for (int c = 0; c < 2; ++c) {
                bf16x8 afr = *(const bf16x8*)&sW[w * 64 * WS + (mt * 16 + l16) * WS + c * 32 + quad * 8];
#pragma unroll
                for (int nt = 0; nt < 2; ++nt)
                    acc[w][mt][nt] = __builtin_amdgcn_mfma_f32_16x16x32_bf16(afr, bfr[c][nt], acc[w][mt][nt], 0, 0, 0);
            }

    unsigned short* Op[3] = {Q, K, V};
    const float* Bp[3] = {bq, bk, bv};
#pragma unroll
    for (int w = 0; w < 3; ++w) {
        unsigned short* op = Op[w] + (size_t)tok * kDG;
#pragma unroll
        for (int mt = 0; mt < 4; ++mt)
#pragma unroll
            for (int nt = 0; nt < 2; ++nt) {
                int g = nt * 16 + l16;
#pragma unroll
                for (int r = 0; r < 4; ++r) {
                    int o = mt * 16 + quad * 4 + r;
                    op[o * kG + g] = (unsigned short)f2bf(acc[w][mt][nt][r] + Bp[w][o * kG + g]);
                }
            }
    }
}

// ---------------- MLP2 GEMM with fused residual+mn+(LN1 next) epilogue -----
template<bool DO_LN>
__global__ __launch_bounds__(256, 2) void mlp2_fused_kernel(
    const unsigned short* __restrict__ Mb,  // [t][32][256] bf16
    const float* __restrict__ W2, const float* __restrict__ b2,
    float* __restrict__ X, const float* __restrict__ gamma,
    const float* __restrict__ lnw, const float* __restrict__ lnb,
    unsigned short* __restrict__ ATout) {
    constexpr int WS = 256 + 8;
    __shared__ short sW[64 * WS];
    const int tid = threadIdx.x, wave = tid >> 6, lane = tid & 63;
    const int l16 = lane & 15, quad = lane >> 4;
    const int tok = blockIdx.x * 4 + wave;

    for (int j = tid * 4; j < 64 * 256; j += 1024) {
        const float4 w4 = *(const float4*)(W2 + j);
        int o = j >> 8, i = j & 255;
        *(short4*)&sW[o * WS + i] = make_short4(f2bf(w4.x), f2bf(w4.y), f2bf(w4.z), f2bf(w4.w));
    }
    __syncthreads();

    f32x4 acc[4][2];
#pragma unroll
    for (int mt = 0; mt < 4; ++mt)
#pragma unroll
        for (int nt = 0; nt < 2; ++nt) acc[mt][nt] = (f32x4){0.f, 0.f, 0.f, 0.f};

    const unsigned short* mp = Mb + (size_t)tok * kG * kE;
#pragma unroll
    for (int c = 0; c < 8; ++c) {
        bf16x8 bfr[2];
#pragma unroll
        for (int nt = 0; nt < 2; ++nt)
            bfr[nt] = *(const bf16x8*)&mp[(nt * 16 + l16) * kE + c * 32 + quad * 8];
#pragma unroll
        for (int mt = 0; mt < 4; ++mt) {
            bf16x8 afr = *(const bf16x8*)&sW[(mt * 16 + l16) * WS + c * 32 + quad * 8];
#pragma unroll
            for (int nt = 0; nt < 2; ++nt)
                acc[mt][nt] = __builtin_amdgcn_mfma_f32_16x16x32_bf16(afr, bfr[nt], acc[mt][nt], 0, 0, 0);
        }
    }

    epi_res_mn_ln(acc, b2, X, X, gamma, lnw, lnb, ATout, tok, l16, quad, DO_LN);
}

// ---------------- MFMA flash-style attention v4 -----------------------------
// REVERT of v3's direct-global fragment loads (latency-bound at 1 block/CU —
// r9 counters: MfmaUtil 2.5%, VALUBusy 4%).  Cooperative coalesced bf16
// staging for Q and K restored (r4-r8 structure); A_T bf16 output kept.
constexpr int QSTR = 264;
constexpr int VSTR = 40;

__global__ __launch_bounds__(256) void attn_mfma_kernel(const unsigned short* __restrict__ Q,
                                                        const unsigned short* __restrict__ K,
                                                        const unsigned short* __restrict__ V,
                                                        unsigned short* __restrict__ AT) {
    __shared__ short sQ[64 * QSTR];      // Q tile, then P, then O bounce
    __shared__ short sKV[256 * VSTR];    // K tiles [32][QSTR] / V^T [256][VSTR]

    const int qt = blockIdx.x, h = blockIdx.y, b = blockIdx.z;
    const int tid = threadIdx.x;
    const int wave = tid >> 6, lane = tid & 63;
    const int l16 = lane & 15, quad = lane >> 4;

    const size_t bh = (size_t)b * kS * kDG + (size_t)h * kHD;

    // stage Q tile (bf16, coalesced 16B/lane)
#pragma unroll
    for (int it = 0; it < 8; ++it) {
        int j = it * 2048 + tid * 8;
        int row = j >> 8, col = j & 255;
        *(bf16x8*)&sQ[row * QSTR + col] =
            *(const bf16x8*)(Q + bh + (size_t)(qt * 64 + row) * kDG + col);
    }
    __syncthreads();

    bf16x8 afrag[8];
    {
        int row = wave * 16 + l16;
#pragma unroll
        for (int c = 0; c < 8; ++c)
            afrag[c] = *(const bf16x8*)&sQ[row * QSTR + c * 32 + quad * 8];
    }

    f32x4 acc[16];
#pragma unroll
    for (int i = 0; i < 16; ++i) acc[i] = (f32x4){0.f, 0.f, 0.f, 0.f};

    for (int kt = 0; kt < 8; ++kt) {
        __syncthreads();
#pragma unroll
        for (int it = 0; it < 4; ++it) {
            int j = it * 2048 + tid * 8;
            int row = j >> 8, col = j & 255;
            *(bf16x8*)&sKV[row * QSTR + col] =
                *(const bf16x8*)(K + bh + (size_t)(kt * 32 + row) * kDG + col);
        }
        __syncthreads();
#pragma unroll
        for (int nt = 0; nt < 2; ++nt) {
            int key = nt * 16 + l16;
            f32x4 a = acc[kt * 2 + nt];
#pragma unroll
            for (int c = 0; c < 8; ++c) {
                bf16x8 bfrag = *(const bf16x8*)&sKV[key * QSTR + c * 32 + quad * 8];
                a = __builtin_amdgcn_mfma_f32_16x16x32_bf16(afrag[c], bfrag, a, 0, 0, 0);
            }
            acc[kt * 2 + nt] = a;
        }
    }

    // softmax over 256 keys (rows = quad*4 + r)
    float inv[4];
#pragma unroll
    for (int r = 0; r < 4; ++r) {
        float m = -1e30f;
#pragma unroll
        for (int t = 0; t < 16; ++t) m = fmaxf(m, acc[t][r]);
#pragma unroll
        for (int off = 1; off < 16; off <<= 1) m = fmaxf(m, __shfl_xor(m, off, 16));
        float s = 0.f;
#pragma unroll
        for (int t = 0; t < 16; ++t) {
            float p = __expf((acc[t][r] - m) * 0.0625f);
            acc[t][r] = p; s += p;
        }
#pragma unroll
        for (int off = 1; off < 16; off <<= 1) s += __shfl_xor(s, off, 16);
        inv[r] = 1.f / s;
    }

    // P (bf16) into sQ — each wave writes only its own 16 rows
#pragma unroll
    for (int t = 0; t < 16; ++t)
#pragma unroll
        for (int r = 0; r < 4; ++r)
            sQ[(wave * 16 + quad * 4 + r) * QSTR + t * 16 + l16] = f2bf(acc[t][r]);

    // PV
    f32x4 oacc[16];
#pragma unroll
    for (int i = 0; i < 16; ++i) oacc[i] = (f32x4){0.f, 0.f, 0.f, 0.f};

    for (int vt = 0; vt < 8; ++vt) {
        __syncthreads();
        {
            int kb = tid >> 5;
#pragma unroll
            for (int it = 0; it < 2; ++it) {
                int db = (tid & 31) + it * 32;
                short4 vr[4];
#pragma unroll
                for (int r = 0; r < 4; ++r)
                    vr[r] = *(const short4*)(V + bh + (size_t)(vt * 32 + kb * 4 + r) * kDG + db * 4);
#pragma unroll
                for (int i = 0; i < 4; ++i) {
                    short4 p = make_short4((&vr[0].x)[i], (&vr[1].x)[i],
                                           (&vr[2].x)[i], (&vr[3].x)[i]);
                    *(short4*)&sKV[(db * 4 + i) * VSTR + kb * 4] = p;
                }
            }
        }
        __syncthreads();
        bf16x8 pfrag = *(const bf16x8*)&sQ[(wave * 16 + l16) * QSTR + vt * 32 + quad * 8];
#pragma unroll
        for (int dt = 0; dt < 16; ++dt) {
            bf16x8 vfrag = *(const bf16x8*)&sKV[(dt * 16 + l16) * VSTR + quad * 8];
            oacc[dt] = __builtin_amdgcn_mfma_f32_16x16x32_bf16(pfrag, vfrag, oacc[dt], 0, 0, 0);
        }
    }

    // O -> LDS bounce in [q][g*8 + i_local] layout (own rows), then A_T write
#pragma unroll
    for (int dt = 0; dt < 16; ++dt)
#pragma unroll
        for (int r = 0; r < 4; ++r) {
            int hd = dt * 16 + l16;
            int g = hd & 31, il = hd >> 5;
            sQ[(wave * 16 + quad * 4 + r) * QSTR + g * 8 + il] = f2bf(oacc[dt][r] * inv[r]);
        }
    __syncthreads();
#pragma unroll
    for (int it = 0; it < 8; ++it) {
        int idx = it * 256 + tid;
        int q = idx >> 5, g = idx & 31;
        size_t dst = ((size_t)(b * kS + qt * 64 + q)) * kDG + g * 64 + h * 8;
        *(bf16x8*)&AT[dst] = *(const bf16x8*)&sQ[q * QSTR + g * 8];
    }
}

// ---------------- in-thread geometric product with compile-time signs -------
constexpr int pc_ce(unsigned v) { int c = 0; while (v) { c += v & 1; v >>= 1; } return c; }
constexpr unsigned gp_mask_ce(int a) {
    unsigned m = 0;
    for (int c = 0; c < 32; ++c) {
        int b = a ^ c;
        int s = (a & b) >> 4;                       // SIG[4] = -1 metric term
        for (int t = a >> 1; t; t >>= 1) s += pc_ce(t & b);
        if (s & 1) m |= (1u << c);
    }
    return m;
}

template<int A>
__device__ __forceinline__ void gp_term(const float* x, const float* y, float* acc) {
    constexpr unsigned m = gp_mask_ce(A);
    const float xa = x[A], nxa = -xa;
#pragma unroll
    for (int c = 0; c < 32; ++c)
        acc[c] = fmaf(((m >> c) & 1u) ? nxa : xa, y[A ^ c], acc[c]);
}

__device__ __forceinline__ void gp_mn_t(const float* x, const float* y, float* out) {
    float acc[32];
#pragma unroll
    for (int c = 0; c < 32; ++c) acc[c] = 0.f;
    gp_term<0>(x, y, acc);  gp_term<1>(x, y, acc);  gp_term<2>(x, y, acc);  gp_term<3>(x, y, acc);
    gp_term<4>(x, y, acc);  gp_term<5>(x, y, acc);  gp_term<6>(x, y, acc);  gp_term<7>(x, y, acc);
    gp_term<8>(x, y, acc);  gp_term<9>(x, y, acc);  gp_term<10>(x, y, acc); gp_term<11>(x, y, acc);
    gp_term<12>(x, y, acc); gp_term<13>(x, y, acc); gp_term<14>(x, y, acc); gp_term<15>(x, y, acc);
    gp_term<16>(x, y, acc); gp_term<17>(x, y, acc); gp_term<18>(x, y, acc); gp_term<19>(x, y, acc);
    gp_term<20>(x, y, acc); gp_term<21>(x, y, acc); gp_term<22>(x, y, acc); gp_term<23>(x, y, acc);
    gp_term<24>(x, y, acc); gp_term<25>(x, y, acc); gp_term<26>(x, y, acc); gp_term<27>(x, y, acc);
    gp_term<28>(x, y, acc); gp_term<29>(x, y, acc); gp_term<30>(x, y, acc); gp_term<31>(x, y, acc);
    float ss = 0.f;
#pragma unroll
    for (int c = 0; c < 32; ++c) ss = fmaf(acc[c], acc[c], ss);
    float r = 1.f / (sqrtf(ss) + 1e-6f);
#pragma unroll
    for (int c = 0; c < 32; ++c) out[c] = acc[c] * r;
}

__device__ __forceinline__ void leaf_load(const float* base, float* v) {
#pragma unroll
    for (int i = 0; i < 8; ++i) {
        const float4 f = *(const float4*)(base + i * 4);
        v[i * 4 + 0] = 0.5f * f.x; v[i * 4 + 1] = 0.5f * f.y;
        v[i * 4 + 2] = 0.5f * f.z; v[i * 4 + 3] = 0.5f * f.w;
    }
    v[0] += 1.f;
    float ss = 0.f;
#pragma unroll
    for (int c = 0; c < 32; ++c) ss = fmaf(v[c], v[c], ss);
    float r = 1.f / (sqrtf(ss) + 1e-6f);
#pragma unroll
    for (int c = 0; c < 32; ++c) v[c] *= r;
}

// ---------------- scan: wave per sequence, rotor per thread -----------------
__global__ __launch_bounds__(256) void scanreg_kernel(const float* __restrict__ DT,
                                                      float* __restrict__ pooled) {
    const int wave = threadIdx.x >> 6, lane = threadIdx.x & 63;
    const int seq = blockIdx.x * 4 + wave;               // b*64 + d
    const float* base = DT + ((size_t)seq * kS + lane * 4) * kG;

    float R[32], Y[32], P[32], Xa[32], Yb[32];

    leaf_load(base, R);
    for (int j = 1; j < 4; ++j) {
        leaf_load(base + j * kG, Y);
        gp_mn_t(Y, R, R);                                // later ∘ earlier
    }

    for (int step = 1; step < 64; step <<= 1) {
        const bool up = lane & step;
#pragma unroll
        for (int c = 0; c < 32; ++c) P[c] = __shfl_xor(R[c], step, 64);
#pragma unroll
        for (int c = 0; c < 32; ++c) {
            Xa[c] = up ? R[c] : P[c];
            Yb[c] = up ? P[c] : R[c];
        }
        gp_mn_t(Xa, Yb, R);
    }

    if (lane == 0) {
        float* op = pooled + (size_t)seq * kG;
#pragma unroll
        for (int i = 0; i < 8; ++i)
            *(float4*)(op + i * 4) = make_float4(R[i * 4], R[i * 4 + 1], R[i * 4 + 2], R[i * 4 + 3]);
    }
}

// ---------------- classifier: wave per class, pooled staged in LDS ----------
__global__ __launch_bounds__(256) void cls2_kernel(const float* __restrict__ P,
                                                   const float* __restrict__ Wc,
                                                   const float* __restrict__ bc,
                                                   float* __restrict__ out) {
    __shared__ float sp[kB * kDG];   // 64 KB
    const int tid = threadIdx.x, wave = tid >> 6, lane = tid & 63;
    for (int j = tid * 4; j < kB * kDG; j += 1024)
        *(float4*)&sp[j] = *(const float4*)(P + j);
    __syncthreads();

    const int c = blockIdx.x * 4 + wave;
    const float* w = Wc + (size_t)c * kDG;
    float acc[kB];
#pragma unroll
    for (int b = 0; b < kB; ++b) acc[b] = 0.f;
#pragma unroll
    for (int cc = 0; cc < 8; ++cc) {
        const float4 w4 = *(const float4*)(w + cc * 256 + lane * 4);
#pragma unroll
        for (int b = 0; b < kB; ++b) {
            const float4 p4 = *(const float4*)&sp[b * kDG + cc * 256 + lane * 4];
            acc[b] += w4.x * p4.x + w4.y * p4.y + w4.z * p4.z + w4.w * p4.w;
        }
    }
#pragma unroll
    for (int b = 0; b < kB; ++b)
#pragma unroll
        for (int off = 32; off > 0; off >>= 1) acc[b] += __shfl_xor(acc[b], off, 64);
    if (lane == 0) {
        float bias = bc[c];
#pragma unroll
        for (int b = 0; b < kB; ++b) out[b * kNC + c] = acc[b] + bias;
    }
}

extern "C" void kernel_launch(void* const* d_in, const int* in_sizes, int n_in,
                              void* d_out, int out_size, void* d_ws, size_t ws_size,
                              hipStream_t stream) {
    const float* x_in = (const float*)d_in[0];
    const float* Wq   = (const float*)d_in[1];
    const float* bq   = (const float*)d_in[2];
    const float* Wk   = (const float*)d_in[3];
    const float* bk   = (const float*)d_in[4];
    const float* Wv   = (const float*)d_in[5];
    const float* bv   = (const float*)d_in[6];
    const float* Wo   = (const float*)d_in[7];
    const float* bo   = (const float*)d_in[8];
    const float* ln1w = (const float*)d_in[9];
    const float* ln1b = (const float*)d_in[10];
    const float* ln2w = (const float*)d_in[11];
    const float* ln2b = (const float*)d_in[12];
    const float* gm1  = (const float*)d_in[13];
    const float* gm2  = (const float*)d_in[14];
    const float* W1   = (const float*)d_in[15];
    const float* b1   = (const float*)d_in[16];
    const float* W2   = (const float*)d_in[17];
    const float* b2   = (const float*)d_in[18];
    const float* Wr   = (const float*)d_in[19];
    const float* br   = (const float*)d_in[20];
    const float* Wc   = (const float*)d_in[21];
    const float* bc   = (const float*)d_in[22];

    const size_t NEL = (size_t)kT * kDG;
    float* F  = (float*)d_ws;
    float* X  = F;                                   // fp32 residual
    unsigned short* Ah = (unsigned short*)(F + NEL); // bf16 A_T (8 MB of region)
    float* DT = F + NEL;                             // fp32 delta^T (same region, after layers)
    unsigned short* Qh = (unsigned short*)(F + 2 * NEL);
    unsigned short* Kh = (unsigned short*)(F + 3 * NEL);
    unsigned short* Vh = (unsigned short*)(F + 4 * NEL);
    unsigned short* Mb = (unsigned short*)(F + 3 * NEL);  // bf16 [t][32][256], spans Kb+Vb
    float* pooled = F + 2 * NEL;                     // Qb region free at scan time

    lnT_kernel<<<kT, 256, 0, stream>>>(x_in, ln1w, ln1b, Ah);

    for (int l = 0; l < 4; l++) {
        gemm_qkv_kernel<<<kT / 4, 256, 0, stream>>>(Ah,
            Wq + l * kD * kD, Wk + l * kD * kD, Wv + l * kD * kD,
            bq + l * kDG, bk + l * kDG, bv + l * kDG, Qh, Kh, Vh);
        attn_mfma_kernel<<<dim3(4, kNH, kB), 256, 0, stream>>>(Qh, Kh, Vh, Ah);
        gemmWo_fused_kernel<<<kT / 4, 256, 0, stream>>>(Ah, Wo + l * kD * kD, bo + l * kDG,
            l == 0 ? x_in : X, gm1 + l * kDG, ln2w + l * kDG, ln2b + l * kDG, X, Ah);
        mlp1_kernel<<<kT / 4, 256, 0, stream>>>(Ah, W1 + l * kE * kD, b1 + l * kE * kG, Mb);
        if (l < 3)
            mlp2_fused_kernel<true><<<kT / 4, 256, 0, stream>>>(Mb, W2 + l * kD * kE, b2 + l * kDG,
                X, gm2 + l * kDG, ln1w + (l + 1) * kDG, ln1b + (l + 1) * kDG, Ah);
        else
            mlp2_fused_kernel<false><<<kT / 4, 256, 0, stream>>>(Mb, W2 + l * kD * kE, b2 + l * kDG,
                X, gm2 + l * kDG, nullptr, nullptr, nullptr);
    }

    // delta (fp32, transposed layout) -> register-resident reduction -> classifier
    vlinT_kernel<<<kT, 256, 0, stream>>>(X, Wr, br, DT);
    scanreg_kernel<<<kB * kD / 4, 256, 0, stream>>>(DT, pooled);
    cls2_kernel<<<kNC / 4, 256, 0, stream>>>(pooled, Wc, bc, (float*)d_out);
}

// Round 12
// 637.420 us; speedup vs baseline: 1.1797x; 1.0316x over previous
//
#include <hip/hip_runtime.h>
#include <hip/hip_bf16.h>

// Problem constants (B=8, S=256, D=64, G=32, E=256, L=4, NH=8, DH=8)
constexpr int kB  = 8;
constexpr int kS  = 256;
constexpr int kD  = 64;
constexpr int kG  = 32;
constexpr int kE  = 256;
constexpr int kNH = 8;
constexpr int kHD = 256;              // DH*G = 8*32
constexpr int kDG = kD * kG;          // 2048
constexpr int kT  = kB * kS;          // 2048 tokens
constexpr int kNC = 1000;

using bf16x8 = __attribute__((ext_vector_type(8))) short;
using f32x4  = __attribute__((ext_vector_type(4))) float;

__device__ __forceinline__ short f2bf(float f) {
    unsigned u = __float_as_uint(f);
    unsigned r = (u + 0x7FFFu + ((u >> 16) & 1u)) >> 16;   // RNE
    return (short)r;
}

__device__ __forceinline__ float tanh_fast(float x) {
    float a = fabsf(x);
    float e = __expf(-2.f * a);
    float t = (1.f - e) / (1.f + e);
    return copysignf(t, x);
}

// ---------------- LN of x_in (layer 0), fp32 A out ----------------
__global__ __launch_bounds__(256) void ln_kernel(const float* __restrict__ Xin,
                                                 const float* __restrict__ w,
                                                 const float* __restrict__ b,
                                                 float* __restrict__ A) {
    int t = blockIdx.x, tid = threadIdx.x;
    const float* xp = Xin + (size_t)t * kDG;
    __shared__ float r1[256], r2[256];
    float v[8], s = 0.f, ss = 0.f;
#pragma unroll
    for (int j = 0; j < 8; j++) {
        float x = xp[tid + j * 256];
        v[j] = x; s += x; ss += x * x;
    }
    r1[tid] = s; r2[tid] = ss; __syncthreads();
    for (int o = 128; o > 0; o >>= 1) {
        if (tid < o) { r1[tid] += r1[tid + o]; r2[tid] += r2[tid + o]; }
        __syncthreads();
    }
    float mean = r1[0] * (1.f / kDG);
    float var  = r2[0] * (1.f / kDG) - mean * mean;
    float rstd = rsqrtf(var + 1e-5f);
    float* ao = A + (size_t)t * kDG;
#pragma unroll
    for (int j = 0; j < 8; j++) {
        int jj = tid + j * 256;
        ao[jj] = (v[j] - mean) * rstd * w[jj] + b[jj];
    }
}

// ---------------- layer-0 Q/K/V GEMM (fp32 A input, bf16 outputs) -----------
__global__ __launch_bounds__(256, 2) void gemm_qkv0_kernel(
    const float* __restrict__ X,
    const float* __restrict__ Wq, const float* __restrict__ Wk, const float* __restrict__ Wv,
    const float* __restrict__ bq, const float* __restrict__ bk, const float* __restrict__ bv,
    unsigned short* __restrict__ Q, unsigned short* __restrict__ K, unsigned short* __restrict__ V) {
    constexpr int WS = 64 + 8;
    __shared__ short sW[3 * 64 * WS];
    __shared__ short sXT[4][32][WS];

    const int tid = threadIdx.x, wave = tid >> 6, lane = tid & 63;
    const int l16 = lane & 15, quad = lane >> 4;
    const int tok = blockIdx.x * 4 + wave;

    const float* Wp[3] = {Wq, Wk, Wv};
#pragma unroll
    for (int w = 0; w < 3; ++w)
        for (int j = tid * 4; j < 64 * 64; j += 1024) {
            const float4 w4 = *(const float4*)(Wp[w] + j);
            int o = j >> 6, i = j & 63;
            *(short4*)&sW[w * 64 * WS + o * WS + i] =
                make_short4(f2bf(w4.x), f2bf(w4.y), f2bf(w4.z), f2bf(w4.w));
        }
    {
        const int g4 = (lane & 7) * 4;
        const int i0 = (lane >> 3) * 8;
        const float* xp = X + (size_t)tok * kDG;
#pragma unroll
        for (int half = 0; half < 2; ++half) {
            float4 vr[4];
#pragma unroll
            for (int r = 0; r < 4; ++r)
                vr[r] = *(const float4*)(xp + (i0 + half * 4 + r) * kG + g4);
#pragma unroll
            for (int gg = 0; gg < 4; ++gg)
                *(short4*)&sXT[wave][g4 + gg][i0 + half * 4] =
                    make_short4(f2bf((&vr[0].x)[gg]), f2bf((&vr[1].x)[gg]),
                                f2bf((&vr[2].x)[gg]), f2bf((&vr[3].x)[gg]));
        }
    }
    __syncthreads();

    bf16x8 bfr[2][2];
#pragma unroll
    for (int c = 0; c < 2; ++c)
#pragma unroll
        for (int nt = 0; nt < 2; ++nt)
            bfr[c][nt] = *(const bf16x8*)&sXT[wave][nt * 16 + l16][c * 32 + quad * 8];

    f32x4 acc[3][4][2];
#pragma unroll
    for (int w = 0; w < 3; ++w)
#pragma unroll
        for (int mt = 0; mt < 4; ++mt)
#pragma unroll
            for (int nt = 0; nt < 2; ++nt) acc[w][mt][nt] = (f32x4){0.f, 0.f, 0.f, 0.f};

#pragma unroll
    for (int w = 0; w < 3; ++w)
#pragma unroll
        for (int mt = 0; mt < 4; ++mt)
#pragma unroll
            for (int c = 0; c < 2; ++c) {
                bf16x8 afr = *(const bf16x8*)&sW[w * 64 * WS + (mt * 16 + l16) * WS + c * 32 + quad * 8];
#pragma unroll
                for (int nt = 0; nt < 2; ++nt)
                    acc[w][mt][nt] = __builtin_amdgcn_mfma_f32_16x16x32_bf16(afr, bfr[c][nt], acc[w][mt][nt], 0, 0, 0);
            }

    unsigned short* Op[3] = {Q, K, V};
    const float* Bp[3] = {bq, bk, bv};
#pragma unroll
    for (int w = 0; w < 3; ++w) {
        unsigned short* op = Op[w] + (size_t)tok * kDG;
#pragma unroll
        for (int mt = 0; mt < 4; ++mt)
#pragma unroll
            for (int nt = 0; nt < 2; ++nt) {
                int g = nt * 16 + l16;
#pragma unroll
                for (int r = 0; r < 4; ++r) {
                    int o = mt * 16 + quad * 4 + r;
                    op[o * kG + g] = (unsigned short)f2bf(acc[w][mt][nt][r] + Bp[w][o * kG + g]);
                }
            }
    }
}

// ---------------- MFMA flash-style attention (r8 version) -------------------
// bf16 Q/K/V in (coalesced staged), fp32 O out [t][d][g].
constexpr int QSTR = 264;
constexpr int VSTR = 40;

__global__ __launch_bounds__(256) void attn_mfma_kernel(const unsigned short* __restrict__ Q,
                                                        const unsigned short* __restrict__ K,
                                                        const unsigned short* __restrict__ V,
                                                        float* __restrict__ O) {
    __shared__ short sQ[64 * QSTR];
    __shared__ short sKV[256 * VSTR];

    const int qt = blockIdx.x, h = blockIdx.y, b = blockIdx.z;
    const int tid = threadIdx.x;
    const int wave = tid >> 6, lane = tid & 63;
    const int l16 = lane & 15, quad = lane >> 4;

    const size_t bh = (size_t)b * kS * kDG + (size_t)h * kHD;

#pragma unroll
    for (int it = 0; it < 8; ++it) {
        int j = it * 2048 + tid * 8;
        int row = j >> 8, col = j & 255;
        *(bf16x8*)&sQ[row * QSTR + col] =
            *(const bf16x8*)(Q + bh + (size_t)(qt * 64 + row) * kDG + col);
    }
    __syncthreads();

    bf16x8 afrag[8];
    {
        int row = wave * 16 + l16;
#pragma unroll
        for (int c = 0; c < 8; ++c)
            afrag[c] = *(const bf16x8*)&sQ[row * QSTR + c * 32 + quad * 8];
    }

    f32x4 acc[16];
#pragma unroll
    for (int i = 0; i < 16; ++i) acc[i] = (f32x4){0.f, 0.f, 0.f, 0.f};

    for (int kt = 0; kt < 8; ++kt) {
        __syncthreads();
#pragma unroll
        for (int it = 0; it < 4; ++it) {
            int j = it * 2048 + tid * 8;
            int row = j >> 8, col = j & 255;
            *(bf16x8*)&sKV[row * QSTR + col] =
                *(const bf16x8*)(K + bh + (size_t)(kt * 32 + row) * kDG + col);
        }
        __syncthreads();
#pragma unroll
        for (int nt = 0; nt < 2; ++nt) {
            int key = nt * 16 + l16;
            f32x4 a = acc[kt * 2 + nt];
#pragma unroll
            for (int c = 0; c < 8; ++c) {
                bf16x8 bfrag = *(const bf16x8*)&sKV[key * QSTR + c * 32 + quad * 8];
                a = __builtin_amdgcn_mfma_f32_16x16x32_bf16(afrag[c], bfrag, a, 0, 0, 0);
            }
            acc[kt * 2 + nt] = a;
        }
    }
    __syncthreads();

    float inv[4];
#pragma unroll
    for (int r = 0; r < 4; ++r) {
        float m = -1e30f;
#pragma unroll
        for (int t = 0; t < 16; ++t) m = fmaxf(m, acc[t][r]);
#pragma unroll
        for (int off = 1; off < 16; off <<= 1) m = fmaxf(m, __shfl_xor(m, off, 16));
        float s = 0.f;
#pragma unroll
        for (int t = 0; t < 16; ++t) {
            float p = __expf((acc[t][r] - m) * 0.0625f);
            acc[t][r] = p; s += p;
        }
#pragma unroll
        for (int off = 1; off < 16; off <<= 1) s += __shfl_xor(s, off, 16);
        inv[r] = 1.f / s;
    }

#pragma unroll
    for (int t = 0; t < 16; ++t)
#pragma unroll
        for (int r = 0; r < 4; ++r)
            sQ[(wave * 16 + quad * 4 + r) * QSTR + t * 16 + l16] = f2bf(acc[t][r]);

    f32x4 oacc[16];
#pragma unroll
    for (int i = 0; i < 16; ++i) oacc[i] = (f32x4){0.f, 0.f, 0.f, 0.f};

    for (int vt = 0; vt < 8; ++vt) {
        __syncthreads();
        {
            int kb = tid >> 5;
#pragma unroll
            for (int it = 0; it < 2; ++it) {
                int db = (tid & 31) + it * 32;
                short4 vr[4];
#pragma unroll
                for (int r = 0; r < 4; ++r)
                    vr[r] = *(const short4*)(V + bh + (size_t)(vt * 32 + kb * 4 + r) * kDG + db * 4);
#pragma unroll
                for (int i = 0; i < 4; ++i) {
                    short4 p = make_short4((&vr[0].x)[i], (&vr[1].x)[i],
                                           (&vr[2].x)[i], (&vr[3].x)[i]);
                    *(short4*)&sKV[(db * 4 + i) * VSTR + kb * 4] = p;
                }
            }
        }
        __syncthreads();
        bf16x8 pfrag = *(const bf16x8*)&sQ[(wave * 16 + l16) * QSTR + vt * 32 + quad * 8];
#pragma unroll
        for (int dt = 0; dt < 16; ++dt) {
            bf16x8 vfrag = *(const bf16x8*)&sKV[(dt * 16 + l16) * VSTR + quad * 8];
            oacc[dt] = __builtin_amdgcn_mfma_f32_16x16x32_bf16(pfrag, vfrag, oacc[dt], 0, 0, 0);
        }
    }

    {
        int qrow = qt * 64 + wave * 16 + quad * 4;
#pragma unroll
        for (int dt = 0; dt < 16; ++dt)
#pragma unroll
            for (int r = 0; r < 4; ++r)
                O[bh + (size_t)(qrow + r) * kDG + dt * 16 + l16] = oacc[dt][r] * inv[r];
    }
}

// ---------------- fused Wo-GEMM + residual/mn/LN2 + MLP1 --------------------
// A2 (LN2 output) never leaves the kernel: epilogue writes it to the wave's
// own LDS slice (same-wave produce/consume, no barrier), MLP1 reads it back
// as B-fragments.  Identical rounding points to the split r8 kernels.
__global__ __launch_bounds__(256, 2) void womlp1_kernel(
    const float* __restrict__ O,        // attn out fp32 [t][64][32]
    const float* __restrict__ Wo, const float* __restrict__ bo,
    const float* __restrict__ Xin, const float* __restrict__ gamma,
    const float* __restrict__ lnw, const float* __restrict__ lnb,
    const float* __restrict__ W1, const float* __restrict__ b1,
    float* __restrict__ Xout, unsigned short* __restrict__ Mb) {
    constexpr int WS = 64 + 8;
    __shared__ short sWo[64 * WS];        // 9.2 KB
    __shared__ short sW1[256 * WS];       // 36.9 KB
    __shared__ short sXT[4][32][WS];      // 18.4 KB: O^T, then reused for A2^T

    const int tid = threadIdx.x, wave = tid >> 6, lane = tid & 63;
    const int l16 = lane & 15, quad = lane >> 4;
    const int tok = blockIdx.x * 4 + wave;

    for (int j = tid * 4; j < 64 * 64; j += 1024) {
        const float4 w4 = *(const float4*)(Wo + j);
        int o = j >> 6, i = j & 63;
        *(short4*)&sWo[o * WS + i] = make_short4(f2bf(w4.x), f2bf(w4.y), f2bf(w4.z), f2bf(w4.w));
    }
    for (int j = tid * 4; j < 256 * 64; j += 1024) {
        const float4 w4 = *(const float4*)(W1 + j);
        int o = j >> 6, i = j & 63;
        *(short4*)&sW1[o * WS + i] = make_short4(f2bf(w4.x), f2bf(w4.y), f2bf(w4.z), f2bf(w4.w));
    }
    {
        const int g4 = (lane & 7) * 4;
        const int i0 = (lane >> 3) * 8;
        const float* xp = O + (size_t)tok * kDG;
#pragma unroll
        for (int half = 0; half < 2; ++half) {
            float4 vr[4];
#pragma unroll
            for (int r = 0; r < 4; ++r)
                vr[r] = *(const float4*)(xp + (i0 + half * 4 + r) * kG + g4);
#pragma unroll
            for (int gg = 0; gg < 4; ++gg)
                *(short4*)&sXT[wave][g4 + gg][i0 + half * 4] =
                    make_short4(f2bf((&vr[0].x)[gg]), f2bf((&vr[1].x)[gg]),
                                f2bf((&vr[2].x)[gg]), f2bf((&vr[3].x)[gg]));
        }
    }
    __syncthreads();

    // ---- Wo GEMM ----
    bf16x8 bfr[2][2];
#pragma unroll
    for (int c = 0; c < 2; ++c)
#pragma unroll
        for (int nt = 0; nt < 2; ++nt)
            bfr[c][nt] = *(const bf16x8*)&sXT[wave][nt * 16 + l16][c * 32 + quad * 8];

    f32x4 acc[4][2];
#pragma unroll
    for (int mt = 0; mt < 4; ++mt)
#pragma unroll
        for (int nt = 0; nt < 2; ++nt) acc[mt][nt] = (f32x4){0.f, 0.f, 0.f, 0.f};
#pragma unroll
    for (int mt = 0; mt < 4; ++mt)
#pragma unroll
        for (int c = 0; c < 2; ++c) {
            bf16x8 afr = *(const bf16x8*)&sWo[(mt * 16 + l16) * WS + c * 32 + quad * 8];
#pragma unroll
            for (int nt = 0; nt < 2; ++nt)
                acc[mt][nt] = __builtin_amdgcn_mfma_f32_16x16x32_bf16(afr, bfr[c][nt], acc[mt][nt], 0, 0, 0);
        }

    // ---- epilogue: X = mn(Xin + gamma*h); A2 = LN2(X) -> sXT[wave] (bf16) ----
    {
        const size_t tb = (size_t)tok * kDG;
        float xv[4][2][4];
        float s = 0.f, ss = 0.f;
#pragma unroll
        for (int mt = 0; mt < 4; ++mt)
#pragma unroll
            for (int r = 0; r < 4; ++r) {
                int o = mt * 16 + quad * 4 + r;
                float vv[2]; float sq = 0.f;
#pragma unroll
                for (int nt = 0; nt < 2; ++nt) {
                    int g = nt * 16 + l16;
                    float h = acc[mt][nt][r] + bo[o * kG + g];
                    float v = Xin[tb + o * kG + g] + gamma[o * kG + g] * h;
                    vv[nt] = v; sq = fmaf(v, v, sq);
                }
#pragma unroll
                for (int off = 1; off < 16; off <<= 1) sq += __shfl_xor(sq, off, 64);
                float rn = 1.f / (sqrtf(sq) + 1e-6f);
#pragma unroll
                for (int nt = 0; nt < 2; ++nt) {
                    int g = nt * 16 + l16;
                    float x = vv[nt] * rn;
                    xv[mt][nt][r] = x;
                    Xout[tb + o * kG + g] = x;
                    s += x; ss = fmaf(x, x, ss);
                }
            }
#pragma unroll
        for (int off = 1; off < 64; off <<= 1) {
            s += __shfl_xor(s, off, 64); ss += __shfl_xor(ss, off, 64);
        }
        float mean = s * (1.f / kDG);
        float var  = ss * (1.f / kDG) - mean * mean;
        float rstd = rsqrtf(var + 1e-5f);
#pragma unroll
        for (int mt = 0; mt < 4; ++mt)
#pragma unroll
            for (int nt = 0; nt < 2; ++nt) {
                int g = nt * 16 + l16;
                short4 s4;
#pragma unroll
                for (int r = 0; r < 4; ++r) {
                    int o = mt * 16 + quad * 4 + r;
                    ((short*)&s4)[r] = f2bf((xv[mt][nt][r] - mean) * rstd * lnw[o * kG + g] + lnb[o * kG + g]);
                }
                *(short4*)&sXT[wave][g][mt * 16 + quad * 4] = s4;   // same-wave slice
            }
    }

    // ---- MLP1 from sXT[wave] (no barrier: same-wave produce/consume) ----
    bf16x8 b2fr[2][2];
#pragma unroll
    for (int c = 0; c < 2; ++c)
#pragma unroll
        for (int nt = 0; nt < 2; ++nt)
            b2fr[c][nt] = *(const bf16x8*)&sXT[wave][nt * 16 + l16][c * 32 + quad * 8];

    f32x4 acc2[16][2];
#pragma unroll
    for (int mt = 0; mt < 16; ++mt)
#pragma unroll
        for (int nt = 0; nt < 2; ++nt) acc2[mt][nt] = (f32x4){0.f, 0.f, 0.f, 0.f};
#pragma unroll
    for (int mt = 0; mt < 16; ++mt)
#pragma unroll
        for (int c = 0; c < 2; ++c) {
            bf16x8 afr = *(const bf16x8*)&sW1[(mt * 16 + l16) * WS + c * 32 + quad * 8];
#pragma unroll
            for (int nt = 0; nt < 2; ++nt)
                acc2[mt][nt] = __builtin_amdgcn_mfma_f32_16x16x32_bf16(afr, b2fr[c][nt], acc2[mt][nt], 0, 0, 0);
        }

    unsigned short* op = Mb + (size_t)tok * kE * kG;   // [t][g][e]
#pragma unroll
    for (int mt = 0; mt < 16; ++mt)
#pragma unroll
        for (int nt = 0; nt < 2; ++nt) {
            int g = nt * 16 + l16;
            int e0 = mt * 16 + quad * 4;
            short4 s4;
            s4.x = f2bf(tanh_fast(acc2[mt][nt][0] + b1[(e0 + 0) * kG + g]));
            s4.y = f2bf(tanh_fast(acc2[mt][nt][1] + b1[(e0 + 1) * kG + g]));
            s4.z = f2bf(tanh_fast(acc2[mt][nt][2] + b1[(e0 + 2) * kG + g]));
            s4.w = f2bf(tanh_fast(acc2[mt][nt][3] + b1[(e0 + 3) * kG + g]));
            *(short4*)&op[g * kE + e0] = s4;
        }
}

// ---------------- fused MLP2 + residual/mn/LN1(next) + QKV(next) ------------
// A1 (next-layer LN1 output) stays in the wave's LDS slice; QKV GEMM of the
// next layer runs in the same kernel.  LDS total 78 KB -> 2 blocks/CU.
__global__ __launch_bounds__(256, 2) void mlp2qkv_kernel(
    const unsigned short* __restrict__ Mb,  // [t][32][256] bf16
    const float* __restrict__ W2, const float* __restrict__ b2,
    float* __restrict__ X, const float* __restrict__ gamma,
    const float* __restrict__ lnw, const float* __restrict__ lnb,
    const float* __restrict__ Wq, const float* __restrict__ Wk, const float* __restrict__ Wv,
    const float* __restrict__ bq, const float* __restrict__ bk, const float* __restrict__ bv,
    unsigned short* __restrict__ Q, unsigned short* __restrict__ K, unsigned short* __restrict__ V) {
    constexpr int W2S = 256 + 8;              // 264
    constexpr int WS  = 64 + 8;               // 72
    __shared__ short sW2[64 * W2S];           // 33.8 KB
    __shared__ short sWqkv[3 * 64 * WS];      // 27.6 KB
    __shared__ short sA1[4][32][WS];          // 18.4 KB

    const int tid = threadIdx.x, wave = tid >> 6, lane = tid & 63;
    const int l16 = lane & 15, quad = lane >> 4;
    const int tok = blockIdx.x * 4 + wave;

    for (int j = tid * 4; j < 64 * 256; j += 1024) {
        const float4 w4 = *(const float4*)(W2 + j);
        int o = j >> 8, i = j & 255;
        *(short4*)&sW2[o * W2S + i] = make_short4(f2bf(w4.x), f2bf(w4.y), f2bf(w4.z), f2bf(w4.w));
    }
    const float* Wp[3] = {Wq, Wk, Wv};
#pragma unroll
    for (int w = 0; w < 3; ++w)
        for (int j = tid * 4; j < 64 * 64; j += 1024) {
            const float4 w4 = *(const float4*)(Wp[w] + j);
            int o = j >> 6, i = j & 63;
            *(short4*)&sWqkv[w * 64 * WS + o * WS + i] =
                make_short4(f2bf(w4.x), f2bf(w4.y), f2bf(w4.z), f2bf(w4.w));
        }
    __syncthreads();

    // ---- MLP2 GEMM (B direct from global Mb) ----
    f32x4 acc[4][2];
#pragma unroll
    for (int mt = 0; mt < 4; ++mt)
#pragma unroll
        for (int nt = 0; nt < 2; ++nt) acc[mt][nt] = (f32x4){0.f, 0.f, 0.f, 0.f};

    const unsigned short* mp = Mb + (size_t)tok * kG * kE;
#pragma unroll
    for (int c = 0; c < 8; ++c) {
        bf16x8 bfr[2];
#pragma unroll
        for (int nt = 0; nt < 2; ++nt)
            bfr[nt] = *(const bf16x8*)&mp[(nt * 16 + l16) * kE + c * 32 + quad * 8];
#pragma unroll
        for (int mt = 0; mt < 4; ++mt) {
            bf16x8 afr = *(const bf16x8*)&sW2[(mt * 16 + l16) * W2S + c * 32 + quad * 8];
#pragma unroll
            for (int nt = 0; nt < 2; ++nt)
                acc[mt][nt] = __builtin_amdgcn_mfma_f32_16x16x32_bf16(afr, bfr[nt], acc[mt][nt], 0, 0, 0);
        }
    }

    // ---- epilogue: X = mn(X + gamma*h); A1 = LN1_next(X) -> sA1[wave] ----
    {
        const size_t tb = (size_t)tok * kDG;
        float xv[4][2][4];
        float s = 0.f, ss = 0.f;
#pragma unroll
        for (int mt = 0; mt < 4; ++mt)
#pragma unroll
            for (int r = 0; r < 4; ++r) {
                int o = mt * 16 + quad * 4 + r;
                float vv[2]; float sq = 0.f;
#pragma unroll
                for (int nt = 0; nt < 2; ++nt) {
                    int g = nt * 16 + l16;
                    float h = acc[mt][nt][r] + b2[o * kG + g];
                    float v = X[tb + o * kG + g] + gamma[o * kG + g] * h;
                    vv[nt] = v; sq = fmaf(v, v, sq);
                }
#pragma unroll
                for (int off = 1; off < 16; off <<= 1) sq += __shfl_xor(sq, off, 64);
                float rn = 1.f / (sqrtf(sq) + 1e-6f);
#pragma unroll
                for (int nt = 0; nt < 2; ++nt) {
                    int g = nt * 16 + l16;
                    float x = vv[nt] * rn;
                    xv[mt][nt][r] = x;
                    X[tb + o * kG + g] = x;
                    s += x; ss = fmaf(x, x, ss);
                }
            }
#pragma unroll
        for (int off = 1; off < 64; off <<= 1) {
            s += __shfl_xor(s, off, 64); ss += __shfl_xor(ss, off, 64);
        }
        float mean = s * (1.f / kDG);
        float var  = ss * (1.f / kDG) - mean * mean;
        float rstd = rsqrtf(var + 1e-5f);
#pragma unroll
        for (int mt = 0; mt < 4; ++mt)
#pragma unroll
            for (int nt = 0; nt < 2; ++nt) {
                int g = nt * 16 + l16;
                short4 s4;
#pragma unroll
                for (int r = 0; r < 4; ++r) {
                    int o = mt * 16 + quad * 4 + r;
                    ((short*)&s4)[r] = f2bf((xv[mt][nt][r] - mean) * rstd * lnw[o * kG + g] + lnb[o * kG + g]);
                }
                *(short4*)&sA1[wave][g][mt * 16 + quad * 4] = s4;
            }
    }

    // ---- next-layer QKV GEMM from sA1[wave] (same-wave, no barrier) ----
    bf16x8 bq1[2][2];
#pragma unroll
    for (int c = 0; c < 2; ++c)
#pragma unroll
        for (int nt = 0; nt < 2; ++nt)
            bq1[c][nt] = *(const bf16x8*)&sA1[wave][nt * 16 + l16][c * 32 + quad * 8];

    f32x4 qacc[3][4][2];
#pragma unroll
    for (int w = 0; w < 3; ++w)
#pragma unroll
        for (int mt = 0; mt < 4; ++mt)
#pragma unroll
            for (int nt = 0; nt < 2; ++nt) qacc[w][mt][nt] = (f32x4){0.f, 0.f, 0.f, 0.f};
#pragma unroll
    for (int w = 0; w < 3; ++w)
#pragma unroll
        for (int mt = 0; mt < 4; ++mt)
#pragma unroll
            for (int c = 0; c < 2; ++c) {
                bf16x8 afr = *(const bf16x8*)&sWqkv[w * 64 * WS + (mt * 16 + l16) * WS + c * 32 + quad * 8];
#pragma unroll
                for (int nt = 0; nt < 2; ++nt)
                    qacc[w][mt][nt] = __builtin_amdgcn_mfma_f32_16x16x32_bf16(afr, bq1[c][nt], qacc[w][mt][nt], 0, 0, 0);
            }

    unsigned short* Op[3] = {Q, K, V};
    const float* Bp[3] = {bq, bk, bv};
#pragma unroll
    for (int w = 0; w < 3; ++w) {
        unsigned short* op = Op[w] + (size_t)tok * kDG;
#pragma unroll
        for (int mt = 0; mt < 4; ++mt)
#pragma unroll
            for (int nt = 0; nt < 2; ++nt) {
                int g = nt * 16 + l16;
#pragma unroll
                for (int r = 0; r < 4; ++r) {
                    int o = mt * 16 + quad * 4 + r;
                    op[o * kG + g] = (unsigned short)f2bf(qacc[w][mt][nt][r] + Bp[w][o * kG + g]);
                }
            }
    }
}

// ---------------- last-layer MLP2 (residual+mn only) ----------------
__global__ __launch_bounds__(256, 2) void mlp2_plain_kernel(
    const unsigned short* __restrict__ Mb,
    const float* __restrict__ W2, const float* __restrict__ b2,
    float* __restrict__ X, const float* __restrict__ gamma) {
    constexpr int W2S = 256 + 8;
    __shared__ short sW2[64 * W2S];
    const int tid = threadIdx.x, wave = tid >> 6, lane = tid & 63;
    const int l16 = lane & 15, quad = lane >> 4;
    const int tok = blockIdx.x * 4 + wave;

    for (int j = tid * 4; j < 64 * 256; j += 1024) {
        const float4 w4 = *(const float4*)(W2 + j);
        int o = j >> 8, i = j & 255;
        *(short4*)&sW2[o * W2S + i] = make_short4(f2bf(w4.x), f2bf(w4.y), f2bf(w4.z), f2bf(w4.w));
    }
    __syncthreads();

    f32x4 acc[4][2];
#pragma unroll
    for (int mt = 0; mt < 4; ++mt)
#pragma unroll
        for (int nt = 0; nt < 2; ++nt) acc[mt][nt] = (f32x4){0.f, 0.f, 0.f, 0.f};

    const unsigned short* mp = Mb + (size_t)tok * kG * kE;
#pragma unroll
    for (int c = 0; c < 8; ++c) {
        bf16x8 bfr[2];
#pragma unroll
        for (int nt = 0; nt < 2; ++nt)
            bfr[nt] = *(const bf16x8*)&mp[(nt * 16 + l16) * kE + c * 32 + quad * 8];
#pragma unroll
        for (int mt = 0; mt < 4; ++mt) {
            bf16x8 afr = *(const bf16x8*)&sW2[(mt * 16 + l16) * W2S + c * 32 + quad * 8];
#pragma unroll
            for (int nt = 0; nt < 2; ++nt)
                acc[mt][nt] = __builtin_amdgcn_mfma_f32_16x16x32_bf16(afr, bfr[nt], acc[mt][nt], 0, 0, 0);
        }
    }

    const size_t tb = (size_t)tok * kDG;
#pragma unroll
    for (int mt = 0; mt < 4; ++mt)
#pragma unroll
        for (int r = 0; r < 4; ++r) {
            int o = mt * 16 + quad * 4 + r;
            float vv[2]; float sq = 0.f;
#pragma unroll
            for (int nt = 0; nt < 2; ++nt) {
                int g = nt * 16 + l16;
                float h = acc[mt][nt][r] + b2[o * kG + g];
                float v = X[tb + o * kG + g] + gamma[o * kG + g] * h;
                vv[nt] = v; sq = fmaf(v, v, sq);
            }
#pragma unroll
            for (int off = 1; off < 16; off <<= 1) sq += __shfl_xor(sq, off, 64);
            float rn = 1.f / (sqrtf(sq) + 1e-6f);
#pragma unroll
            for (int nt = 0; nt < 2; ++nt) {
                int g = nt * 16 + l16;
                X[tb + o * kG + g] = vv[nt] * rn;
            }
        }
}

// ---------------- scalar fp32 versor_linear, TRANSPOSED output --------------
__global__ __launch_bounds__(256) void vlinT_kernel(const float* __restrict__ X,
                                                    const float* __restrict__ W,
                                                    const float* __restrict__ bias,
                                                    float* __restrict__ OutT) {
    __shared__ float sx[kDG];
    __shared__ float sw[kD * kD];
    int t = blockIdx.x, tid = threadIdx.x;
    const float* xp = X + (size_t)t * kDG;
    for (int j = tid; j < kDG; j += 256) sx[j] = xp[j];
    for (int j = tid; j < kD * kD; j += 256) sw[j] = W[j];
    __syncthreads();
    int g = tid & 31, ob = tid >> 5;
    int b = t >> 8, s = t & 255;
    float* op = OutT + ((size_t)b * kD * kS + s) * kG;
    for (int o = ob; o < kD; o += 8) {
        float acc = bias[o * kG + g];
        const float* wr = sw + o * kD;
#pragma unroll
        for (int i = 0; i < kD; i++) acc += wr[i] * sx[i * kG + g];
        op[(size_t)o * kS * kG + g] = acc;
    }
}

// ---------------- in-thread geometric product with compile-time signs -------
constexpr int pc_ce(unsigned v) { int c = 0; while (v) { c += v & 1; v >>= 1; } return c; }
constexpr unsigned gp_mask_ce(int a) {
    unsigned m = 0;
    for (int c = 0; c < 32; ++c) {
        int b = a ^ c;
        int s = (a & b) >> 4;
        for (int t = a >> 1; t; t >>= 1) s += pc_ce(t & b);
        if (s & 1) m |= (1u << c);
    }
    return m;
}

template<int A>
__device__ __forceinline__ void gp_term(const float* x, const float* y, float* acc) {
    constexpr unsigned m = gp_mask_ce(A);
    const float xa = x[A], nxa = -xa;
#pragma unroll
    for (int c = 0; c < 32; ++c)
        acc[c] = fmaf(((m >> c) & 1u) ? nxa : xa, y[A ^ c], acc[c]);
}

__device__ __forceinline__ void gp_mn_t(const float* x, const float* y, float* out) {
    float acc[32];
#pragma unroll
    for (int c = 0; c < 32; ++c) acc[c] = 0.f;
    gp_term<0>(x, y, acc);  gp_term<1>(x, y, acc);  gp_term<2>(x, y, acc);  gp_term<3>(x, y, acc);
    gp_term<4>(x, y, acc);  gp_term<5>(x, y, acc);  gp_term<6>(x, y, acc);  gp_term<7>(x, y, acc);
    gp_term<8>(x, y, acc);  gp_term<9>(x, y, acc);  gp_term<10>(x, y, acc); gp_term<11>(x, y, acc);
    gp_term<12>(x, y, acc); gp_term<13>(x, y, acc); gp_term<14>(x, y, acc); gp_term<15>(x, y, acc);
    gp_term<16>(x, y, acc); gp_term<17>(x, y, acc); gp_term<18>(x, y, acc); gp_term<19>(x, y, acc);
    gp_term<20>(x, y, acc); gp_term<21>(x, y, acc); gp_term<22>(x, y, acc); gp_term<23>(x, y, acc);
    gp_term<24>(x, y, acc); gp_term<25>(x, y, acc); gp_term<26>(x, y, acc); gp_term<27>(x, y, acc);
    gp_term<28>(x, y, acc); gp_term<29>(x, y, acc); gp_term<30>(x, y, acc); gp_term<31>(x, y, acc);
    float ss = 0.f;
#pragma unroll
    for (int c = 0; c < 32; ++c) ss = fmaf(acc[c], acc[c], ss);
    float r = 1.f / (sqrtf(ss) + 1e-6f);
#pragma unroll
    for (int c = 0; c < 32; ++c) out[c] = acc[c] * r;
}

__device__ __forceinline__ void leaf_load(const float* base, float* v) {
#pragma unroll
    for (int i = 0; i < 8; ++i) {
        const float4 f = *(const float4*)(base + i * 4);
        v[i * 4 + 0] = 0.5f * f.x; v[i * 4 + 1] = 0.5f * f.y;
        v[i * 4 + 2] = 0.5f * f.z; v[i * 4 + 3] = 0.5f * f.w;
    }
    v[0] += 1.f;
    float ss = 0.f;
#pragma unroll
    for (int c = 0; c < 32; ++c) ss = fmaf(v[c], v[c], ss);
    float r = 1.f / (sqrtf(ss) + 1e-6f);
#pragma unroll
    for (int c = 0; c < 32; ++c) v[c] *= r;
}

// ---------------- scan: wave per sequence, rotor per thread -----------------
__global__ __launch_bounds__(256) void scanreg_kernel(const float* __restrict__ DT,
                                                      float* __restrict__ pooled) {
    const int wave = threadIdx.x >> 6, lane = threadIdx.x & 63;
    const int seq = blockIdx.x * 4 + wave;
    const float* base = DT + ((size_t)seq * kS + lane * 4) * kG;

    float R[32], Y[32], P[32], Xa[32], Yb[32];

    leaf_load(base, R);
    for (int j = 1; j < 4; ++j) {
        leaf_load(base + j * kG, Y);
        gp_mn_t(Y, R, R);
    }

    for (int step = 1; step < 64; step <<= 1) {
        const bool up = lane & step;
#pragma unroll
        for (int c = 0; c < 32; ++c) P[c] = __shfl_xor(R[c], step, 64);
#pragma unroll
        for (int c = 0; c < 32; ++c) {
            Xa[c] = up ? R[c] : P[c];
            Yb[c] = up ? P[c] : R[c];
        }
        gp_mn_t(Xa, Yb, R);
    }

    if (lane == 0) {
        float* op = pooled + (size_t)seq * kG;
#pragma unroll
        for (int i = 0; i < 8; ++i)
            *(float4*)(op + i * 4) = make_float4(R[i * 4], R[i * 4 + 1], R[i * 4 + 2], R[i * 4 + 3]);
    }
}

// ---------------- classifier ----------------
__global__ __launch_bounds__(256) void cls2_kernel(const float* __restrict__ P,
                                                   const float* __restrict__ Wc,
                                                   const float* __restrict__ bc,
                                                   float* __restrict__ out) {
    __shared__ float sp[kB * kDG];
    const int tid = threadIdx.x, wave = tid >> 6, lane = tid & 63;
    for (int j = tid * 4; j < kB * kDG; j += 1024)
        *(float4*)&sp[j] = *(const float4*)(P + j);
    __syncthreads();

    const int c = blockIdx.x * 4 + wave;
    const float* w = Wc + (size_t)c * kDG;
    float acc[kB];
#pragma unroll
    for (int b = 0; b < kB; ++b) acc[b] = 0.f;
#pragma unroll
    for (int cc = 0; cc < 8; ++cc) {
        const float4 w4 = *(const float4*)(w + cc * 256 + lane * 4);
#pragma unroll
        for (int b = 0; b < kB; ++b) {
            const float4 p4 = *(const float4*)&sp[b * kDG + cc * 256 + lane * 4];
            acc[b] += w4.x * p4.x + w4.y * p4.y + w4.z * p4.z + w4.w * p4.w;
        }
    }
#pragma unroll
    for (int b = 0; b < kB; ++b)
#pragma unroll
        for (int off = 32; off > 0; off >>= 1) acc[b] += __shfl_xor(acc[b], off, 64);
    if (lane == 0) {
        float bias = bc[c];
#pragma unroll
        for (int b = 0; b < kB; ++b) out[b * kNC + c] = acc[b] + bias;
    }
}

extern "C" void kernel_launch(void* const* d_in, const int* in_sizes, int n_in,
                              void* d_out, int out_size, void* d_ws, size_t ws_size,
                              hipStream_t stream) {
    const float* x_in = (const float*)d_in[0];
    const float* Wq   = (const float*)d_in[1];
    const float* bq   = (const float*)d_in[2];
    const float* Wk   = (const float*)d_in[3];
    const float* bk   = (const float*)d_in[4];
    const float* Wv   = (const float*)d_in[5];
    const float* bv   = (const float*)d_in[6];
    const float* Wo   = (const float*)d_in[7];
    const float* bo   = (const float*)d_in[8];
    const float* ln1w = (const float*)d_in[9];
    const float* ln1b = (const float*)d_in[10];
    const float* ln2w = (const float*)d_in[11];
    const float* ln2b = (const float*)d_in[12];
    const float* gm1  = (const float*)d_in[13];
    const float* gm2  = (const float*)d_in[14];
    const float* W1   = (const float*)d_in[15];
    const float* b1   = (const float*)d_in[16];
    const float* W2   = (const float*)d_in[17];
    const float* b2   = (const float*)d_in[18];
    const float* Wr   = (const float*)d_in[19];
    const float* br   = (const float*)d_in[20];
    const float* Wc   = (const float*)d_in[21];
    const float* bc   = (const float*)d_in[22];

    const size_t NEL = (size_t)kT * kDG;     // 4M floats / region
    float* F  = (float*)d_ws;
    float* X  = F;                           // region 0: fp32 residual
    float* Ob = F + NEL;                     // region 1: fp32 LN-A (l0) / attn-O / DT
    unsigned short* Qh = (unsigned short*)(F + 2 * NEL);
    unsigned short* Kh = (unsigned short*)(F + 3 * NEL);
    unsigned short* Vh = (unsigned short*)(F + 4 * NEL);
    unsigned short* Mb = (unsigned short*)(F + 5 * NEL);  // bf16 [t][32][256], spans regions 5-6
    float* DT = Ob;
    float* pooled = F + 2 * NEL;

    ln_kernel<<<kT, 256, 0, stream>>>(x_in, ln1w, ln1b, Ob);
    gemm_qkv0_kernel<<<kT / 4, 256, 0, stream>>>(Ob, Wq, Wk, Wv, bq, bk, bv, Qh, Kh, Vh);

    for (int l = 0; l < 4; l++) {
        attn_mfma_kernel<<<dim3(4, kNH, kB), 256, 0, stream>>>(Qh, Kh, Vh, Ob);
        womlp1_kernel<<<kT / 4, 256, 0, stream>>>(Ob, Wo + l * kD * kD, bo + l * kDG,
            l == 0 ? x_in : X, gm1 + l * kDG, ln2w + l * kDG, ln2b + l * kDG,
            W1 + l * kE * kD, b1 + l * kE * kG, X, Mb);
        if (l < 3)
            mlp2qkv_kernel<<<kT / 4, 256, 0, stream>>>(Mb, W2 + l * kD * kE, b2 + l * kDG,
                X, gm2 + l * kDG, ln1w + (l + 1) * kDG, ln1b + (l + 1) * kDG,
                Wq + (l + 1) * kD * kD, Wk + (l + 1) * kD * kD, Wv + (l + 1) * kD * kD,
                bq + (l + 1) * kDG, bk + (l + 1) * kDG, bv + (l + 1) * kDG, Qh, Kh, Vh);
        else
            mlp2_plain_kernel<<<kT / 4, 256, 0, stream>>>(Mb, W2 + l * kD * kE, b2 + l * kDG,
                X, gm2 + l * kDG);
    }

    // delta (fp32, transposed layout) -> register-resident reduction -> classifier
    vlinT_kernel<<<kT, 256, 0, stream>>>(X, Wr, br, DT);
    scanreg_kernel<<<kB * kD / 4, 256, 0, stream>>>(DT, pooled);
    cls2_kernel<<<kNC / 4, 256, 0, stream>>>(pooled, Wc, bc, (float*)d_out);
}

// Round 13
// 560.590 us; speedup vs baseline: 1.3414x; 1.1371x over previous
//
#include <hip/hip_runtime.h>
#include <hip/hip_bf16.h>

// Problem constants (B=8, S=256, D=64, G=32, E=256, L=4, NH=8, DH=8)
constexpr int kB  = 8;
constexpr int kS  = 256;
constexpr int kD  = 64;
constexpr int kG  = 32;
constexpr int kE  = 256;
constexpr int kNH = 8;
constexpr int kHD = 256;              // DH*G = 8*32
constexpr int kDG = kD * kG;          // 2048
constexpr int kT  = kB * kS;          // 2048 tokens
constexpr int kNC = 1000;

using bf16x8 = __attribute__((ext_vector_type(8))) short;
using f32x4  = __attribute__((ext_vector_type(4))) float;

__device__ __forceinline__ short f2bf(float f) {
    unsigned u = __float_as_uint(f);
    unsigned r = (u + 0x7FFFu + ((u >> 16) & 1u)) >> 16;   // RNE
    return (short)r;
}

__device__ __forceinline__ float tanh_fast(float x) {
    float a = fabsf(x);
    float e = __expf(-2.f * a);
    float t = (1.f - e) / (1.f + e);
    return copysignf(t, x);
}

// ---------------- one-time weight fp32->bf16 conversion ----------------
// dst layout: [Wq 16384][Wk 16384][Wv 16384][Wo 16384][W1 65536][W2 65536]
__global__ __launch_bounds__(256) void cvtw_kernel(
    const float* __restrict__ Wq, const float* __restrict__ Wk,
    const float* __restrict__ Wv, const float* __restrict__ Wo,
    const float* __restrict__ W1, const float* __restrict__ W2,
    unsigned short* __restrict__ dst) {
    int idx = (blockIdx.x * 256 + threadIdx.x) * 4;
    const float* src; int off;
    if      (idx <  16384) { src = Wq; off = 0; }
    else if (idx <  32768) { src = Wk; off = 16384; }
    else if (idx <  49152) { src = Wv; off = 32768; }
    else if (idx <  65536) { src = Wo; off = 49152; }
    else if (idx < 131072) { src = W1; off = 65536; }
    else                   { src = W2; off = 131072; }
    const float4 v = *(const float4*)(src + (idx - off));
    *(short4*)&dst[idx] = make_short4(f2bf(v.x), f2bf(v.y), f2bf(v.z), f2bf(v.w));
}

// ---------------- LN of x_in (layer 0), fp32 A out ----------------
__global__ __launch_bounds__(256) void ln_kernel(const float* __restrict__ Xin,
                                                 const float* __restrict__ w,
                                                 const float* __restrict__ b,
                                                 float* __restrict__ A) {
    int t = blockIdx.x, tid = threadIdx.x;
    const float* xp = Xin + (size_t)t * kDG;
    __shared__ float r1[256], r2[256];
    float v[8], s = 0.f, ss = 0.f;
#pragma unroll
    for (int j = 0; j < 8; j++) {
        float x = xp[tid + j * 256];
        v[j] = x; s += x; ss += x * x;
    }
    r1[tid] = s; r2[tid] = ss; __syncthreads();
    for (int o = 128; o > 0; o >>= 1) {
        if (tid < o) { r1[tid] += r1[tid + o]; r2[tid] += r2[tid + o]; }
        __syncthreads();
    }
    float mean = r1[0] * (1.f / kDG);
    float var  = r2[0] * (1.f / kDG) - mean * mean;
    float rstd = rsqrtf(var + 1e-5f);
    float* ao = A + (size_t)t * kDG;
#pragma unroll
    for (int j = 0; j < 8; j++) {
        int jj = tid + j * 256;
        ao[jj] = (v[j] - mean) * rstd * w[jj] + b[jj];
    }
}

// ---------------- fused epilogue: residual + mn + (optional) next LN -------
__device__ __forceinline__ void epi_res_mn_ln(
    const f32x4 (&acc)[4][2], const float* __restrict__ bias,
    const float* __restrict__ Xin, float* __restrict__ Xout,
    const float* __restrict__ gamma,
    const float* __restrict__ lnw, const float* __restrict__ lnb,
    float* __restrict__ Aout, int tok, int l16, int quad, bool do_ln) {
    const size_t tb = (size_t)tok * kDG;
    float xv[4][2][4];
    float s = 0.f, ss = 0.f;
#pragma unroll
    for (int mt = 0; mt < 4; ++mt)
#pragma unroll
        for (int r = 0; r < 4; ++r) {
            int o = mt * 16 + quad * 4 + r;
            float vv[2]; float sq = 0.f;
#pragma unroll
            for (int nt = 0; nt < 2; ++nt) {
                int g = nt * 16 + l16;
                float h = acc[mt][nt][r] + bias[o * kG + g];
                float v = Xin[tb + o * kG + g] + gamma[o * kG + g] * h;
                vv[nt] = v; sq = fmaf(v, v, sq);
            }
#pragma unroll
            for (int off = 1; off < 16; off <<= 1) sq += __shfl_xor(sq, off, 64);
            float rn = 1.f / (sqrtf(sq) + 1e-6f);
#pragma unroll
            for (int nt = 0; nt < 2; ++nt) {
                int g = nt * 16 + l16;
                float x = vv[nt] * rn;
                xv[mt][nt][r] = x;
                Xout[tb + o * kG + g] = x;
                s += x; ss = fmaf(x, x, ss);
            }
        }
    if (!do_ln) return;
#pragma unroll
    for (int off = 1; off < 64; off <<= 1) {
        s += __shfl_xor(s, off, 64); ss += __shfl_xor(ss, off, 64);
    }
    float mean = s * (1.f / kDG);
    float var  = ss * (1.f / kDG) - mean * mean;
    float rstd = rsqrtf(var + 1e-5f);
#pragma unroll
    for (int mt = 0; mt < 4; ++mt)
#pragma unroll
        for (int nt = 0; nt < 2; ++nt) {
            int g = nt * 16 + l16;
#pragma unroll
            for (int r = 0; r < 4; ++r) {
                int o = mt * 16 + quad * 4 + r;
                Aout[tb + o * kG + g] = (xv[mt][nt][r] - mean) * rstd * lnw[o * kG + g] + lnb[o * kG + g];
            }
        }
}

// ---------------- scalar fp32 versor_linear, TRANSPOSED output --------------
__global__ __launch_bounds__(256) void vlinT_kernel(const float* __restrict__ X,
                                                    const float* __restrict__ W,
                                                    const float* __restrict__ bias,
                                                    float* __restrict__ OutT) {
    __shared__ float sx[kDG];
    __shared__ float sw[kD * kD];
    int t = blockIdx.x, tid = threadIdx.x;
    const float* xp = X + (size_t)t * kDG;
    for (int j = tid; j < kDG; j += 256) sx[j] = xp[j];
    for (int j = tid; j < kD * kD; j += 256) sw[j] = W[j];
    __syncthreads();
    int g = tid & 31, ob = tid >> 5;
    int b = t >> 8, s = t & 255;
    float* op = OutT + ((size_t)b * kD * kS + s) * kG;
    for (int o = ob; o < kD; o += 8) {
        float acc = bias[o * kG + g];
        const float* wr = sw + o * kD;
#pragma unroll
        for (int i = 0; i < kD; i++) acc += wr[i] * sx[i * kG + g];
        op[(size_t)o * kS * kG + g] = acc;
    }
}

// ---------------- MLP1 GEMM (M=256, tanh, bf16 [t][g][e] out) --------------
__global__ __launch_bounds__(256, 2) void mlp1_kernel(
    const float* __restrict__ X, const unsigned short* __restrict__ Wh,
    const float* __restrict__ bias, unsigned short* __restrict__ outH) {
    constexpr int M = 256;
    constexpr int WS = 64 + 8;
    __shared__ short sW[M * WS];
    __shared__ short sXT[4][32][WS];

    const int tid = threadIdx.x, wave = tid >> 6, lane = tid & 63;
    const int l16 = lane & 15, quad = lane >> 4;
    const int tok = blockIdx.x * 4 + wave;

    for (int j = tid * 8; j < M * 64; j += 2048) {
        int o = j >> 6, i = j & 63;
        *(bf16x8*)&sW[o * WS + i] = *(const bf16x8*)(Wh + j);
    }
    {
        const int g4 = (lane & 7) * 4;
        const int i0 = (lane >> 3) * 8;
        const float* xp = X + (size_t)tok * kDG;
#pragma unroll
        for (int half = 0; half < 2; ++half) {
            float4 vr[4];
#pragma unroll
            for (int r = 0; r < 4; ++r)
                vr[r] = *(const float4*)(xp + (i0 + half * 4 + r) * kG + g4);
#pragma unroll
            for (int gg = 0; gg < 4; ++gg)
                *(short4*)&sXT[wave][g4 + gg][i0 + half * 4] =
                    make_short4(f2bf((&vr[0].x)[gg]), f2bf((&vr[1].x)[gg]),
                                f2bf((&vr[2].x)[gg]), f2bf((&vr[3].x)[gg]));
        }
    }
    __syncthreads();

    bf16x8 bfr[2][2];
#pragma unroll
    for (int c = 0; c < 2; ++c)
#pragma unroll
        for (int nt = 0; nt < 2; ++nt)
            bfr[c][nt] = *(const bf16x8*)&sXT[wave][nt * 16 + l16][c * 32 + quad * 8];

    f32x4 acc[16][2];
#pragma unroll
    for (int mt = 0; mt < 16; ++mt)
#pragma unroll
        for (int nt = 0; nt < 2; ++nt) acc[mt][nt] = (f32x4){0.f, 0.f, 0.f, 0.f};

#pragma unroll
    for (int mt = 0; mt < 16; ++mt)
#pragma unroll
        for (int c = 0; c < 2; ++c) {
            bf16x8 afr = *(const bf16x8*)&sW[(mt * 16 + l16) * WS + c * 32 + quad * 8];
#pragma unroll
            for (int nt = 0; nt < 2; ++nt)
                acc[mt][nt] = __builtin_amdgcn_mfma_f32_16x16x32_bf16(afr, bfr[c][nt], acc[mt][nt], 0, 0, 0);
        }

    unsigned short* op = outH + (size_t)tok * M * kG;   // [t][g][M]
#pragma unroll
    for (int mt = 0; mt < 16; ++mt)
#pragma unroll
        for (int nt = 0; nt < 2; ++nt) {
            int g = nt * 16 + l16;
            int e0 = mt * 16 + quad * 4;
            short4 s4;
            s4.x = f2bf(tanh_fast(acc[mt][nt][0] + bias[(e0 + 0) * kG + g]));
            s4.y = f2bf(tanh_fast(acc[mt][nt][1] + bias[(e0 + 1) * kG + g]));
            s4.z = f2bf(tanh_fast(acc[mt][nt][2] + bias[(e0 + 2) * kG + g]));
            s4.w = f2bf(tanh_fast(acc[mt][nt][3] + bias[(e0 + 3) * kG + g]));
            *(short4*)&op[g * M + e0] = s4;
        }
}

// ---------------- Wo GEMM with fused residual+mn+LN2 epilogue ---------------
__global__ __launch_bounds__(256, 2) void gemmWo_fused_kernel(
    const float* __restrict__ X, const unsigned short* __restrict__ Wh,
    const float* __restrict__ bias,
    const float* __restrict__ Xin, const float* __restrict__ gamma,
    const float* __restrict__ lnw, const float* __restrict__ lnb,
    float* __restrict__ Xout, float* __restrict__ Aout) {
    constexpr int WS = 64 + 8;
    __shared__ short sW[64 * WS];
    __shared__ short sXT[4][32][WS];

    const int tid = threadIdx.x, wave = tid >> 6, lane = tid & 63;
    const int l16 = lane & 15, quad = lane >> 4;
    const int tok = blockIdx.x * 4 + wave;

    for (int j = tid * 8; j < 64 * 64; j += 2048) {
        int o = j >> 6, i = j & 63;
        *(bf16x8*)&sW[o * WS + i] = *(const bf16x8*)(Wh + j);
    }
    {
        const int g4 = (lane & 7) * 4;
        const int i0 = (lane >> 3) * 8;
        const float* xp = X + (size_t)tok * kDG;
#pragma unroll
        for (int half = 0; half < 2; ++half) {
            float4 vr[4];
#pragma unroll
            for (int r = 0; r < 4; ++r)
                vr[r] = *(const float4*)(xp + (i0 + half * 4 + r) * kG + g4);
#pragma unroll
            for (int gg = 0; gg < 4; ++gg)
                *(short4*)&sXT[wave][g4 + gg][i0 + half * 4] =
                    make_short4(f2bf((&vr[0].x)[gg]), f2bf((&vr[1].x)[gg]),
                                f2bf((&vr[2].x)[gg]), f2bf((&vr[3].x)[gg]));
        }
    }
    __syncthreads();

    bf16x8 bfr[2][2];
#pragma unroll
    for (int c = 0; c < 2; ++c)
#pragma unroll
        for (int nt = 0; nt < 2; ++nt)
            bfr[c][nt] = *(const bf16x8*)&sXT[wave][nt * 16 + l16][c * 32 + quad * 8];

    f32x4 acc[4][2];
#pragma unroll
    for (int mt = 0; mt < 4; ++mt)
#pragma unroll
        for (int nt = 0; nt < 2; ++nt) acc[mt][nt] = (f32x4){0.f, 0.f, 0.f, 0.f};

#pragma unroll
    for (int mt = 0; mt < 4; ++mt)
#pragma unroll
        for (int c = 0; c < 2; ++c) {
            bf16x8 afr = *(const bf16x8*)&sW[(mt * 16 + l16) * WS + c * 32 + quad * 8];
#pragma unroll
            for (int nt = 0; nt < 2; ++nt)
                acc[mt][nt] = __builtin_amdgcn_mfma_f32_16x16x32_bf16(afr, bfr[c][nt], acc[mt][nt], 0, 0, 0);
        }

    epi_res_mn_ln(acc, bias, Xin, Xout, gamma, lnw, lnb, Aout, tok, l16, quad, true);
}

// ---------------- fused Q/K/V GEMM -> bf16 outputs ----------------
__global__ __launch_bounds__(256, 2) void gemm_qkv_kernel(
    const float* __restrict__ X,
    const unsigned short* __restrict__ Wqh, const unsigned short* __restrict__ Wkh,
    const unsigned short* __restrict__ Wvh,
    const float* __restrict__ bq, const float* __restrict__ bk, const float* __restrict__ bv,
    unsigned short* __restrict__ Q, unsigned short* __restrict__ K, unsigned short* __restrict__ V) {
    constexpr int WS = 64 + 8;
    __shared__ short sW[3 * 64 * WS];
    __shared__ short sXT[4][32][WS];

    const int tid = threadIdx.x, wave = tid >> 6, lane = tid & 63;
    const int l16 = lane & 15, quad = lane >> 4;
    const int tok = blockIdx.x * 4 + wave;

    const unsigned short* Wp[3] = {Wqh, Wkh, Wvh};
#pragma unroll
    for (int w = 0; w < 3; ++w)
        for (int j = tid * 8; j < 64 * 64; j += 2048) {
            int o = j >> 6, i = j & 63;
            *(bf16x8*)&sW[w * 64 * WS + o * WS + i] = *(const bf16x8*)(Wp[w] + j);
        }
    {
        const int g4 = (lane & 7) * 4;
        const int i0 = (lane >> 3) * 8;
        const float* xp = X + (size_t)tok * kDG;
#pragma unroll
        for (int half = 0; half < 2; ++half) {
            float4 vr[4];
#pragma unroll
            for (int r = 0; r < 4; ++r)
                vr[r] = *(const float4*)(xp + (i0 + half * 4 + r) * kG + g4);
#pragma unroll
            for (int gg = 0; gg < 4; ++gg)
                *(short4*)&sXT[wave][g4 + gg][i0 + half * 4] =
                    make_short4(f2bf((&vr[0].x)[gg]), f2bf((&vr[1].x)[gg]),
                                f2bf((&vr[2].x)[gg]), f2bf((&vr[3].x)[gg]));
        }
    }
    __syncthreads();

    bf16x8 bfr[2][2];
#pragma unroll
    for (int c = 0; c < 2; ++c)
#pragma unroll
        for (int nt = 0; nt < 2; ++nt)
            bfr[c][nt] = *(const bf16x8*)&sXT[wave][nt * 16 + l16][c * 32 + quad * 8];

    f32x4 acc[3][4][2];
#pragma unroll
    for (int w = 0; w < 3; ++w)
#pragma unroll
        for (int mt = 0; mt < 4; ++mt)
#pragma unroll
            for (int nt = 0; nt < 2; ++nt) acc[w][mt][nt] = (f32x4){0.f, 0.f, 0.f, 0.f};

#pragma unroll
    for (int w = 0; w < 3; ++w)
#pragma unroll
        for (int mt = 0; mt < 4; ++mt)
#pragma unroll
            for (int c = 0; c < 2; ++c) {
                bf16x8 afr = *(const bf16x8*)&sW[w * 64 * WS + (mt * 16 + l16) * WS + c * 32 + quad * 8];
#pragma unroll
                for (int nt = 0; nt < 2; ++nt)
                    acc[w][mt][nt] = __builtin_amdgcn_mfma_f32_16x16x32_bf16(afr, bfr[c][nt], acc[w][mt][nt], 0, 0, 0);
            }

    unsigned short* Op[3] = {Q, K, V};
    const float* Bp[3] = {bq, bk, bv};
#pragma unroll
    for (int w = 0; w < 3; ++w) {
        unsigned short* op = Op[w] + (size_t)tok * kDG;
#pragma unroll
        for (int mt = 0; mt < 4; ++mt)
#pragma unroll
            for (int nt = 0; nt < 2; ++nt) {
                int g = nt * 16 + l16;
#pragma unroll
                for (int r = 0; r < 4; ++r) {
                    int o = mt * 16 + quad * 4 + r;
                    op[o * kG + g] = (unsigned short)f2bf(acc[w][mt][nt][r] + Bp[w][o * kG + g]);
                }
            }
    }
}

// ---------------- MLP2 GEMM with fused residual+mn+(LN1 next) epilogue -----
template<bool DO_LN>
__global__ __launch_bounds__(256, 2) void mlp2_fused_kernel(
    const unsigned short* __restrict__ Mb,  // [t][32][256] bf16
    const unsigned short* __restrict__ W2h, const float* __restrict__ b2,
    float* __restrict__ X, const float* __restrict__ gamma,
    const float* __restrict__ lnw, const float* __restrict__ lnb,
    float* __restrict__ Aout) {
    constexpr int WS = 256 + 8;
    __shared__ short sW[64 * WS];
    const int tid = threadIdx.x, wave = tid >> 6, lane = tid & 63;
    const int l16 = lane & 15, quad = lane >> 4;
    const int tok = blockIdx.x * 4 + wave;

    for (int j = tid * 8; j < 64 * 256; j += 2048) {
        int o = j >> 8, i = j & 255;
        *(bf16x8*)&sW[o * WS + i] = *(const bf16x8*)(W2h + j);
    }
    __syncthreads();

    f32x4 acc[4][2];
#pragma unroll
    for (int mt = 0; mt < 4; ++mt)
#pragma unroll
        for (int nt = 0; nt < 2; ++nt) acc[mt][nt] = (f32x4){0.f, 0.f, 0.f, 0.f};

    const unsigned short* mp = Mb + (size_t)tok * kG * kE;
#pragma unroll
    for (int c = 0; c < 8; ++c) {
        bf16x8 bfr[2];
#pragma unroll
        for (int nt = 0; nt < 2; ++nt)
            bfr[nt] = *(const bf16x8*)&mp[(nt * 16 + l16) * kE + c * 32 + quad * 8];
#pragma unroll
        for (int mt = 0; mt < 4; ++mt) {
            bf16x8 afr = *(const bf16x8*)&sW[(mt * 16 + l16) * WS + c * 32 + quad * 8];
#pragma unroll
            for (int nt = 0; nt < 2; ++nt)
                acc[mt][nt] = __builtin_amdgcn_mfma_f32_16x16x32_bf16(afr, bfr[nt], acc[mt][nt], 0, 0, 0);
        }
    }

    epi_res_mn_ln(acc, b2, X, X, gamma, lnw, lnb, Aout, tok, l16, quad, DO_LN);
}

// ---------------- MFMA attention with register double-buffer prefetch ------
// 1 block/CU (grid 256) means no inter-block latency hiding -> explicitly
// prefetch next K/V tile into VGPRs while MFMA-ing the current LDS tile.
constexpr int QSTR = 264;
constexpr int VSTR = 40;

__global__ __launch_bounds__(256) void attn_mfma_kernel(const unsigned short* __restrict__ Q,
                                                        const unsigned short* __restrict__ K,
                                                        const unsigned short* __restrict__ V,
                                                        float* __restrict__ O) {
    __shared__ short sQ[64 * QSTR];
    __shared__ short sKV[256 * VSTR];

    const int qt = blockIdx.x, h = blockIdx.y, b = blockIdx.z;
    const int tid = threadIdx.x;
    const int wave = tid >> 6, lane = tid & 63;
    const int l16 = lane & 15, quad = lane >> 4;

    const size_t bh = (size_t)b * kS * kDG + (size_t)h * kHD;

    // stage Q tile + prefetch K tile 0 (independent, overlapped)
#pragma unroll
    for (int it = 0; it < 8; ++it) {
        int j = it * 2048 + tid * 8;
        int row = j >> 8, col = j & 255;
        *(bf16x8*)&sQ[row * QSTR + col] =
            *(const bf16x8*)(Q + bh + (size_t)(qt * 64 + row) * kDG + col);
    }
    bf16x8 kpre[4];
#pragma unroll
    for (int it = 0; it < 4; ++it) {
        int j = it * 2048 + tid * 8;
        int row = j >> 8, col = j & 255;
        kpre[it] = *(const bf16x8*)(K + bh + (size_t)row * kDG + col);
    }
    __syncthreads();

    bf16x8 afrag[8];
    {
        int row = wave * 16 + l16;
#pragma unroll
        for (int c = 0; c < 8; ++c)
            afrag[c] = *(const bf16x8*)&sQ[row * QSTR + c * 32 + quad * 8];
    }

    f32x4 acc[16];
#pragma unroll
    for (int i = 0; i < 16; ++i) acc[i] = (f32x4){0.f, 0.f, 0.f, 0.f};

    for (int kt = 0; kt < 8; ++kt) {
        // store prefetched K tile (prev tile consumed: trailing barrier)
#pragma unroll
        for (int it = 0; it < 4; ++it) {
            int j = it * 2048 + tid * 8;
            int row = j >> 8, col = j & 255;
            *(bf16x8*)&sKV[row * QSTR + col] = kpre[it];
        }
        __syncthreads();
        if (kt < 7) {
#pragma unroll
            for (int it = 0; it < 4; ++it) {
                int j = it * 2048 + tid * 8;
                int row = j >> 8, col = j & 255;
                kpre[it] = *(const bf16x8*)(K + bh + (size_t)((kt + 1) * 32 + row) * kDG + col);
            }
        }
#pragma unroll
        for (int nt = 0; nt < 2; ++nt) {
            int key = nt * 16 + l16;
            f32x4 a = acc[kt * 2 + nt];
#pragma unroll
            for (int c = 0; c < 8; ++c) {
                bf16x8 bfrag = *(const bf16x8*)&sKV[key * QSTR + c * 32 + quad * 8];
                a = __builtin_amdgcn_mfma_f32_16x16x32_bf16(afrag[c], bfrag, a, 0, 0, 0);
            }
            acc[kt * 2 + nt] = a;
        }
        __syncthreads();   // tile consumed before next store
    }

    // softmax over 256 keys (rows = quad*4 + r)
    float inv[4];
#pragma unroll
    for (int r = 0; r < 4; ++r) {
        float m = -1e30f;
#pragma unroll
        for (int t = 0; t < 16; ++t) m = fmaxf(m, acc[t][r]);
#pragma unroll
        for (int off = 1; off < 16; off <<= 1) m = fmaxf(m, __shfl_xor(m, off, 16));
        float s = 0.f;
#pragma unroll
        for (int t = 0; t < 16; ++t) {
            float p = __expf((acc[t][r] - m) * 0.0625f);
            acc[t][r] = p; s += p;
        }
#pragma unroll
        for (int off = 1; off < 16; off <<= 1) s += __shfl_xor(s, off, 16);
        inv[r] = 1.f / s;
    }

    // P (bf16) into sQ (each wave its own rows; pfrag reads same-wave)
#pragma unroll
    for (int t = 0; t < 16; ++t)
#pragma unroll
        for (int r = 0; r < 4; ++r)
            sQ[(wave * 16 + quad * 4 + r) * QSTR + t * 16 + l16] = f2bf(acc[t][r]);

    // prefetch V tile 0
    short4 vpre[8];
    {
        int kb = tid >> 5;
#pragma unroll
        for (int it = 0; it < 2; ++it) {
            int db = (tid & 31) + it * 32;
#pragma unroll
            for (int r = 0; r < 4; ++r)
                vpre[it * 4 + r] = *(const short4*)(V + bh + (size_t)(kb * 4 + r) * kDG + db * 4);
        }
    }

    f32x4 oacc[16];
#pragma unroll
    for (int i = 0; i < 16; ++i) oacc[i] = (f32x4){0.f, 0.f, 0.f, 0.f};

    for (int vt = 0; vt < 8; ++vt) {
        __syncthreads();   // K-phase done (vt=0) / prev V tile consumed
        {
            int kb = tid >> 5;
#pragma unroll
            for (int it = 0; it < 2; ++it) {
                int db = (tid & 31) + it * 32;
#pragma unroll
                for (int i = 0; i < 4; ++i) {
                    short4 p = make_short4((&vpre[it * 4 + 0].x)[i], (&vpre[it * 4 + 1].x)[i],
                                           (&vpre[it * 4 + 2].x)[i], (&vpre[it * 4 + 3].x)[i]);
                    *(short4*)&sKV[(db * 4 + i) * VSTR + kb * 4] = p;
                }
            }
        }
        __syncthreads();
        if (vt < 7) {
            int kb = tid >> 5;
#pragma unroll
            for (int it = 0; it < 2; ++it) {
                int db = (tid & 31) + it * 32;
#pragma unroll
                for (int r = 0; r < 4; ++r)
                    vpre[it * 4 + r] = *(const short4*)(V + bh + (size_t)((vt + 1) * 32 + kb * 4 + r) * kDG + db * 4);
            }
        }
        bf16x8 pfrag = *(const bf16x8*)&sQ[(wave * 16 + l16) * QSTR + vt * 32 + quad * 8];
#pragma unroll
        for (int dt = 0; dt < 16; ++dt) {
            bf16x8 vfrag = *(const bf16x8*)&sKV[(dt * 16 + l16) * VSTR + quad * 8];
            oacc[dt] = __builtin_amdgcn_mfma_f32_16x16x32_bf16(pfrag, vfrag, oacc[dt], 0, 0, 0);
        }
    }

    {
        int qrow = qt * 64 + wave * 16 + quad * 4;
#pragma unroll
        for (int dt = 0; dt < 16; ++dt)
#pragma unroll
            for (int r = 0; r < 4; ++r)
                O[bh + (size_t)(qrow + r) * kDG + dt * 16 + l16] = oacc[dt][r] * inv[r];
    }
}

// ---------------- in-thread geometric product with compile-time signs -------
constexpr int pc_ce(unsigned v) { int c = 0; while (v) { c += v & 1; v >>= 1; } return c; }
constexpr unsigned gp_mask_ce(int a) {
    unsigned m = 0;
    for (int c = 0; c < 32; ++c) {
        int b = a ^ c;
        int s = (a & b) >> 4;
        for (int t = a >> 1; t; t >>= 1) s += pc_ce(t & b);
        if (s & 1) m |= (1u << c);
    }
    return m;
}

template<int A>
__device__ __forceinline__ void gp_term(const float* x, const float* y, float* acc) {
    constexpr unsigned m = gp_mask_ce(A);
    const float xa = x[A], nxa = -xa;
#pragma unroll
    for (int c = 0; c < 32; ++c)
        acc[c] = fmaf(((m >> c) & 1u) ? nxa : xa, y[A ^ c], acc[c]);
}

__device__ __forceinline__ void gp_mn_t(const float* x, const float* y, float* out) {
    float acc[32];
#pragma unroll
    for (int c = 0; c < 32; ++c) acc[c] = 0.f;
    gp_term<0>(x, y, acc);  gp_term<1>(x, y, acc);  gp_term<2>(x, y, acc);  gp_term<3>(x, y, acc);
    gp_term<4>(x, y, acc);  gp_term<5>(x, y, acc);  gp_term<6>(x, y, acc);  gp_term<7>(x, y, acc);
    gp_term<8>(x, y, acc);  gp_term<9>(x, y, acc);  gp_term<10>(x, y, acc); gp_term<11>(x, y, acc);
    gp_term<12>(x, y, acc); gp_term<13>(x, y, acc); gp_term<14>(x, y, acc); gp_term<15>(x, y, acc);
    gp_term<16>(x, y, acc); gp_term<17>(x, y, acc); gp_term<18>(x, y, acc); gp_term<19>(x, y, acc);
    gp_term<20>(x, y, acc); gp_term<21>(x, y, acc); gp_term<22>(x, y, acc); gp_term<23>(x, y, acc);
    gp_term<24>(x, y, acc); gp_term<25>(x, y, acc); gp_term<26>(x, y, acc); gp_term<27>(x, y, acc);
    gp_term<28>(x, y, acc); gp_term<29>(x, y, acc); gp_term<30>(x, y, acc); gp_term<31>(x, y, acc);
    float ss = 0.f;
#pragma unroll
    for (int c = 0; c < 32; ++c) ss = fmaf(acc[c], acc[c], ss);
    float r = 1.f / (sqrtf(ss) + 1e-6f);
#pragma unroll
    for (int c = 0; c < 32; ++c) out[c] = acc[c] * r;
}

__device__ __forceinline__ void leaf_load(const float* base, float* v) {
#pragma unroll
    for (int i = 0; i < 8; ++i) {
        const float4 f = *(const float4*)(base + i * 4);
        v[i * 4 + 0] = 0.5f * f.x; v[i * 4 + 1] = 0.5f * f.y;
        v[i * 4 + 2] = 0.5f * f.z; v[i * 4 + 3] = 0.5f * f.w;
    }
    v[0] += 1.f;
    float ss = 0.f;
#pragma unroll
    for (int c = 0; c < 32; ++c) ss = fmaf(v[c], v[c], ss);
    float r = 1.f / (sqrtf(ss) + 1e-6f);
#pragma unroll
    for (int c = 0; c < 32; ++c) v[c] *= r;
}

// ---------------- scan: wave per sequence, rotor per thread -----------------
__global__ __launch_bounds__(256) void scanreg_kernel(const float* __restrict__ DT,
                                                      float* __restrict__ pooled) {
    const int wave = threadIdx.x >> 6, lane = threadIdx.x & 63;
    const int seq = blockIdx.x * 4 + wave;
    const float* base = DT + ((size_t)seq * kS + lane * 4) * kG;

    float R[32], Y[32], P[32], Xa[32], Yb[32];

    leaf_load(base, R);
    for (int j = 1; j < 4; ++j) {
        leaf_load(base + j * kG, Y);
        gp_mn_t(Y, R, R);
    }

    for (int step = 1; step < 64; step <<= 1) {
        const bool up = lane & step;
#pragma unroll
        for (int c = 0; c < 32; ++c) P[c] = __shfl_xor(R[c], step, 64);
#pragma unroll
        for (int c = 0; c < 32; ++c) {
            Xa[c] = up ? R[c] : P[c];
            Yb[c] = up ? P[c] : R[c];
        }
        gp_mn_t(Xa, Yb, R);
    }

    if (lane == 0) {
        float* op = pooled + (size_t)seq * kG;
#pragma unroll
        for (int i = 0; i < 8; ++i)
            *(float4*)(op + i * 4) = make_float4(R[i * 4], R[i * 4 + 1], R[i * 4 + 2], R[i * 4 + 3]);
    }
}

// ---------------- classifier ----------------
__global__ __launch_bounds__(256) void cls2_kernel(const float* __restrict__ P,
                                                   const float* __restrict__ Wc,
                                                   const float* __restrict__ bc,
                                                   float* __restrict__ out) {
    __shared__ float sp[kB * kDG];
    const int tid = threadIdx.x, wave = tid >> 6, lane = tid & 63;
    for (int j = tid * 4; j < kB * kDG; j += 1024)
        *(float4*)&sp[j] = *(const float4*)(P + j);
    __syncthreads();

    const int c = blockIdx.x * 4 + wave;
    const float* w = Wc + (size_t)c * kDG;
    float acc[kB];
#pragma unroll
    for (int b = 0; b < kB; ++b) acc[b] = 0.f;
#pragma unroll
    for (int cc = 0; cc < 8; ++cc) {
        const float4 w4 = *(const float4*)(w + cc * 256 + lane * 4);
#pragma unroll
        for (int b = 0; b < kB; ++b) {
            const float4 p4 = *(const float4*)&sp[b * kDG + cc * 256 + lane * 4];
            acc[b] += w4.x * p4.x + w4.y * p4.y + w4.z * p4.z + w4.w * p4.w;
        }
    }
#pragma unroll
    for (int b = 0; b < kB; ++b)
#pragma unroll
        for (int off = 32; off > 0; off >>= 1) acc[b] += __shfl_xor(acc[b], off, 64);
    if (lane == 0) {
        float bias = bc[c];
#pragma unroll
        for (int b = 0; b < kB; ++b) out[b * kNC + c] = acc[b] + bias;
    }
}

extern "C" void kernel_launch(void* const* d_in, const int* in_sizes, int n_in,
                              void* d_out, int out_size, void* d_ws, size_t ws_size,
                              hipStream_t stream) {
    const float* x_in = (const float*)d_in[0];
    const float* Wq   = (const float*)d_in[1];
    const float* bq   = (const float*)d_in[2];
    const float* Wk   = (const float*)d_in[3];
    const float* bk   = (const float*)d_in[4];
    const float* Wv   = (const float*)d_in[5];
    const float* bv   = (const float*)d_in[6];
    const float* Wo   = (const float*)d_in[7];
    const float* bo   = (const float*)d_in[8];
    const float* ln1w = (const float*)d_in[9];
    const float* ln1b = (const float*)d_in[10];
    const float* ln2w = (const float*)d_in[11];
    const float* ln2b = (const float*)d_in[12];
    const float* gm1  = (const float*)d_in[13];
    const float* gm2  = (const float*)d_in[14];
    const float* W1   = (const float*)d_in[15];
    const float* b1   = (const float*)d_in[16];
    const float* W2   = (const float*)d_in[17];
    const float* b2   = (const float*)d_in[18];
    const float* Wr   = (const float*)d_in[19];
    const float* br   = (const float*)d_in[20];
    const float* Wc   = (const float*)d_in[21];
    const float* bc   = (const float*)d_in[22];

    const size_t NEL = (size_t)kT * kDG;
    float* F  = (float*)d_ws;
    float* X  = F;                                   // region 0
    float* A  = F + NEL;                             // region 1 (LN out / attn O / DT)
    unsigned short* Qh = (unsigned short*)(F + 2 * NEL);
    unsigned short* Kh = (unsigned short*)(F + 3 * NEL);
    unsigned short* Vh = (unsigned short*)(F + 4 * NEL);
    unsigned short* Mb = (unsigned short*)(F + 3 * NEL);   // spans regions 3-4
    unsigned short* Wb = (unsigned short*)(F + 5 * NEL);   // bf16 weights (384 KB)
    float* pooled = F + 2 * NEL;
    float* DT = A;

    // bf16 weight copies: [Wq|Wk|Wv|Wo: 16384 each][W1: 65536][W2: 65536]
    cvtw_kernel<<<192, 256, 0, stream>>>(Wq, Wk, Wv, Wo, W1, W2, Wb);
    unsigned short* Wqh = Wb;
    unsigned short* Wkh = Wb + 16384;
    unsigned short* Wvh = Wb + 32768;
    unsigned short* Woh = Wb + 49152;
    unsigned short* W1h = Wb + 65536;
    unsigned short* W2h = Wb + 131072;

    ln_kernel<<<kT, 256, 0, stream>>>(x_in, ln1w, ln1b, A);

    for (int l = 0; l < 4; l++) {
        gemm_qkv_kernel<<<kT / 4, 256, 0, stream>>>(A,
            Wqh + l * 4096, Wkh + l * 4096, Wvh + l * 4096,
            bq + l * kDG, bk + l * kDG, bv + l * kDG, Qh, Kh, Vh);
        attn_mfma_kernel<<<dim3(4, kNH, kB), 256, 0, stream>>>(Qh, Kh, Vh, A);
        gemmWo_fused_kernel<<<kT / 4, 256, 0, stream>>>(A, Woh + l * 4096, bo + l * kDG,
            l == 0 ? x_in : X, gm1 + l * kDG, ln2w + l * kDG, ln2b + l * kDG, X, A);
        mlp1_kernel<<<kT / 4, 256, 0, stream>>>(A, W1h + l * 16384, b1 + l * kE * kG, Mb);
        if (l < 3)
            mlp2_fused_kernel<true><<<kT / 4, 256, 0, stream>>>(Mb, W2h + l * 16384, b2 + l * kDG,
                X, gm2 + l * kDG, ln1w + (l + 1) * kDG, ln1b + (l + 1) * kDG, A);
        else
            mlp2_fused_kernel<false><<<kT / 4, 256, 0, stream>>>(Mb, W2h + l * 16384, b2 + l * kDG,
                X, gm2 + l * kDG, nullptr, nullptr, nullptr);
    }

    // delta (fp32, transposed) -> register-resident reduction -> classifier
    vlinT_kernel<<<kT, 256, 0, stream>>>(X, Wr, br, DT);
    scanreg_kernel<<<kB * kD / 4, 256, 0, stream>>>(DT, pooled);
    cls2_kernel<<<kNC / 4, 256, 0, stream>>>(pooled, Wc, bc, (float*)d_out);
}

// Round 14
// 539.291 us; speedup vs baseline: 1.3943x; 1.0395x over previous
//
#include <hip/hip_runtime.h>
#include <hip/hip_bf16.h>

// Problem constants (B=8, S=256, D=64, G=32, E=256, L=4, NH=8, DH=8)
constexpr int kB  = 8;
constexpr int kS  = 256;
constexpr int kD  = 64;
constexpr int kG  = 32;
constexpr int kE  = 256;
constexpr int kNH = 8;
constexpr int kHD = 256;              // DH*G = 8*32
constexpr int kDG = kD * kG;          // 2048
constexpr int kT  = kB * kS;          // 2048 tokens
constexpr int kNC = 1000;

using bf16x8 = __attribute__((ext_vector_type(8))) short;
using f32x4  = __attribute__((ext_vector_type(4))) float;

__device__ __forceinline__ short f2bf(float f) {
    unsigned u = __float_as_uint(f);
    unsigned r = (u + 0x7FFFu + ((u >> 16) & 1u)) >> 16;   // RNE
    return (short)r;
}

__device__ __forceinline__ float tanh_fast(float x) {
    float a = fabsf(x);
    float e = __expf(-2.f * a);
    float t = (1.f - e) / (1.f + e);
    return copysignf(t, x);
}

// ---------------- one-time weight fp32->bf16 conversion ----------------
__global__ __launch_bounds__(256) void cvtw_kernel(
    const float* __restrict__ Wq, const float* __restrict__ Wk,
    const float* __restrict__ Wv, const float* __restrict__ Wo,
    const float* __restrict__ W1, const float* __restrict__ W2,
    unsigned short* __restrict__ dst) {
    int idx = (blockIdx.x * 256 + threadIdx.x) * 4;
    const float* src; int off;
    if      (idx <  16384) { src = Wq; off = 0; }
    else if (idx <  32768) { src = Wk; off = 16384; }
    else if (idx <  49152) { src = Wv; off = 32768; }
    else if (idx <  65536) { src = Wo; off = 49152; }
    else if (idx < 131072) { src = W1; off = 65536; }
    else                   { src = W2; off = 131072; }
    const float4 v = *(const float4*)(src + (idx - off));
    *(short4*)&dst[idx] = make_short4(f2bf(v.x), f2bf(v.y), f2bf(v.z), f2bf(v.w));
}

// ---------------- LN of x_in (layer 0), fp32 A out ----------------
__global__ __launch_bounds__(256) void ln_kernel(const float* __restrict__ Xin,
                                                 const float* __restrict__ w,
                                                 const float* __restrict__ b,
                                                 float* __restrict__ A) {
    int t = blockIdx.x, tid = threadIdx.x;
    const float* xp = Xin + (size_t)t * kDG;
    __shared__ float r1[256], r2[256];
    float v[8], s = 0.f, ss = 0.f;
#pragma unroll
    for (int j = 0; j < 8; j++) {
        float x = xp[tid + j * 256];
        v[j] = x; s += x; ss += x * x;
    }
    r1[tid] = s; r2[tid] = ss; __syncthreads();
    for (int o = 128; o > 0; o >>= 1) {
        if (tid < o) { r1[tid] += r1[tid + o]; r2[tid] += r2[tid + o]; }
        __syncthreads();
    }
    float mean = r1[0] * (1.f / kDG);
    float var  = r2[0] * (1.f / kDG) - mean * mean;
    float rstd = rsqrtf(var + 1e-5f);
    float* ao = A + (size_t)t * kDG;
#pragma unroll
    for (int j = 0; j < 8; j++) {
        int jj = tid + j * 256;
        ao[jj] = (v[j] - mean) * rstd * w[jj] + b[jj];
    }
}

// ---------------- fused epilogue: residual + mn + (optional) next LN -------
__device__ __forceinline__ void epi_res_mn_ln(
    const f32x4 (&acc)[4][2], const float* __restrict__ bias,
    const float* __restrict__ Xin, float* __restrict__ Xout,
    const float* __restrict__ gamma,
    const float* __restrict__ lnw, const float* __restrict__ lnb,
    float* __restrict__ Aout, int tok, int l16, int quad, bool do_ln) {
    const size_t tb = (size_t)tok * kDG;
    float xv[4][2][4];
    float s = 0.f, ss = 0.f;
#pragma unroll
    for (int mt = 0; mt < 4; ++mt)
#pragma unroll
        for (int r = 0; r < 4; ++r) {
            int o = mt * 16 + quad * 4 + r;
            float vv[2]; float sq = 0.f;
#pragma unroll
            for (int nt = 0; nt < 2; ++nt) {
                int g = nt * 16 + l16;
                float h = acc[mt][nt][r] + bias[o * kG + g];
                float v = Xin[tb + o * kG + g] + gamma[o * kG + g] * h;
                vv[nt] = v; sq = fmaf(v, v, sq);
            }
#pragma unroll
            for (int off = 1; off < 16; off <<= 1) sq += __shfl_xor(sq, off, 64);
            float rn = 1.f / (sqrtf(sq) + 1e-6f);
#pragma unroll
            for (int nt = 0; nt < 2; ++nt) {
                int g = nt * 16 + l16;
                float x = vv[nt] * rn;
                xv[mt][nt][r] = x;
                Xout[tb + o * kG + g] = x;
                s += x; ss = fmaf(x, x, ss);
            }
        }
    if (!do_ln) return;
#pragma unroll
    for (int off = 1; off < 64; off <<= 1) {
        s += __shfl_xor(s, off, 64); ss += __shfl_xor(ss, off, 64);
    }
    float mean = s * (1.f / kDG);
    float var  = ss * (1.f / kDG) - mean * mean;
    float rstd = rsqrtf(var + 1e-5f);
#pragma unroll
    for (int mt = 0; mt < 4; ++mt)
#pragma unroll
        for (int nt = 0; nt < 2; ++nt) {
            int g = nt * 16 + l16;
#pragma unroll
            for (int r = 0; r < 4; ++r) {
                int o = mt * 16 + quad * 4 + r;
                Aout[tb + o * kG + g] = (xv[mt][nt][r] - mean) * rstd * lnw[o * kG + g] + lnb[o * kG + g];
            }
        }
}

// ---------------- scalar fp32 versor_linear, TRANSPOSED output --------------
__global__ __launch_bounds__(256) void vlinT_kernel(const float* __restrict__ X,
                                                    const float* __restrict__ W,
                                                    const float* __restrict__ bias,
                                                    float* __restrict__ OutT) {
    __shared__ float sx[kDG];
    __shared__ float sw[kD * kD];
    int t = blockIdx.x, tid = threadIdx.x;
    const float* xp = X + (size_t)t * kDG;
    for (int j = tid; j < kDG; j += 256) sx[j] = xp[j];
    for (int j = tid; j < kD * kD; j += 256) sw[j] = W[j];
    __syncthreads();
    int g = tid & 31, ob = tid >> 5;
    int b = t >> 8, s = t & 255;
    float* op = OutT + ((size_t)b * kD * kS + s) * kG;
    for (int o = ob; o < kD; o += 8) {
        float acc = bias[o * kG + g];
        const float* wr = sw + o * kD;
#pragma unroll
        for (int i = 0; i < kD; i++) acc += wr[i] * sx[i * kG + g];
        op[(size_t)o * kS * kG + g] = acc;
    }
}

// ---------------- MLP1 GEMM (M=256, tanh, bf16 [t][g][e] out) --------------
__global__ __launch_bounds__(256, 2) void mlp1_kernel(
    const float* __restrict__ X, const unsigned short* __restrict__ Wh,
    const float* __restrict__ bias, unsigned short* __restrict__ outH) {
    constexpr int M = 256;
    constexpr int WS = 64 + 8;
    __shared__ short sW[M * WS];
    __shared__ short sXT[4][32][WS];

    const int tid = threadIdx.x, wave = tid >> 6, lane = tid & 63;
    const int l16 = lane & 15, quad = lane >> 4;
    const int tok = blockIdx.x * 4 + wave;

    for (int j = tid * 8; j < M * 64; j += 2048) {
        int o = j >> 6, i = j & 63;
        *(bf16x8*)&sW[o * WS + i] = *(const bf16x8*)(Wh + j);
    }
    {
        const int g4 = (lane & 7) * 4;
        const int i0 = (lane >> 3) * 8;
        const float* xp = X + (size_t)tok * kDG;
#pragma unroll
        for (int half = 0; half < 2; ++half) {
            float4 vr[4];
#pragma unroll
            for (int r = 0; r < 4; ++r)
                vr[r] = *(const float4*)(xp + (i0 + half * 4 + r) * kG + g4);
#pragma unroll
            for (int gg = 0; gg < 4; ++gg)
                *(short4*)&sXT[wave][g4 + gg][i0 + half * 4] =
                    make_short4(f2bf((&vr[0].x)[gg]), f2bf((&vr[1].x)[gg]),
                                f2bf((&vr[2].x)[gg]), f2bf((&vr[3].x)[gg]));
        }
    }
    __syncthreads();

    bf16x8 bfr[2][2];
#pragma unroll
    for (int c = 0; c < 2; ++c)
#pragma unroll
        for (int nt = 0; nt < 2; ++nt)
            bfr[c][nt] = *(const bf16x8*)&sXT[wave][nt * 16 + l16][c * 32 + quad * 8];

    f32x4 acc[16][2];
#pragma unroll
    for (int mt = 0; mt < 16; ++mt)
#pragma unroll
        for (int nt = 0; nt < 2; ++nt) acc[mt][nt] = (f32x4){0.f, 0.f, 0.f, 0.f};

#pragma unroll
    for (int mt = 0; mt < 16; ++mt)
#pragma unroll
        for (int c = 0; c < 2; ++c) {
            bf16x8 afr = *(const bf16x8*)&sW[(mt * 16 + l16) * WS + c * 32 + quad * 8];
#pragma unroll
            for (int nt = 0; nt < 2; ++nt)
                acc[mt][nt] = __builtin_amdgcn_mfma_f32_16x16x32_bf16(afr, bfr[c][nt], acc[mt][nt], 0, 0, 0);
        }

    unsigned short* op = outH + (size_t)tok * M * kG;   // [t][g][M]
#pragma unroll
    for (int mt = 0; mt < 16; ++mt)
#pragma unroll
        for (int nt = 0; nt < 2; ++nt) {
            int g = nt * 16 + l16;
            int e0 = mt * 16 + quad * 4;
            short4 s4;
            s4.x = f2bf(tanh_fast(acc[mt][nt][0] + bias[(e0 + 0) * kG + g]));
            s4.y = f2bf(tanh_fast(acc[mt][nt][1] + bias[(e0 + 1) * kG + g]));
            s4.z = f2bf(tanh_fast(acc[mt][nt][2] + bias[(e0 + 2) * kG + g]));
            s4.w = f2bf(tanh_fast(acc[mt][nt][3] + bias[(e0 + 3) * kG + g]));
            *(short4*)&op[g * M + e0] = s4;
        }
}

// ---------------- Wo GEMM with fused residual+mn+LN2 epilogue ---------------
__global__ __launch_bounds__(256, 3) void gemmWo_fused_kernel(
    const float* __restrict__ X, const unsigned short* __restrict__ Wh,
    const float* __restrict__ bias,
    const float* __restrict__ Xin, const float* __restrict__ gamma,
    const float* __restrict__ lnw, const float* __restrict__ lnb,
    float* __restrict__ Xout, float* __restrict__ Aout) {
    constexpr int WS = 64 + 8;
    __shared__ short sW[64 * WS];
    __shared__ short sXT[4][32][WS];

    const int tid = threadIdx.x, wave = tid >> 6, lane = tid & 63;
    const int l16 = lane & 15, quad = lane >> 4;
    const int tok = blockIdx.x * 4 + wave;

    for (int j = tid * 8; j < 64 * 64; j += 2048) {
        int o = j >> 6, i = j & 63;
        *(bf16x8*)&sW[o * WS + i] = *(const bf16x8*)(Wh + j);
    }
    {
        const int g4 = (lane & 7) * 4;
        const int i0 = (lane >> 3) * 8;
        const float* xp = X + (size_t)tok * kDG;
#pragma unroll
        for (int half = 0; half < 2; ++half) {
            float4 vr[4];
#pragma unroll
            for (int r = 0; r < 4; ++r)
                vr[r] = *(const float4*)(xp + (i0 + half * 4 + r) * kG + g4);
#pragma unroll
            for (int gg = 0; gg < 4; ++gg)
                *(short4*)&sXT[wave][g4 + gg][i0 + half * 4] =
                    make_short4(f2bf((&vr[0].x)[gg]), f2bf((&vr[1].x)[gg]),
                                f2bf((&vr[2].x)[gg]), f2bf((&vr[3].x)[gg]));
        }
    }
    __syncthreads();

    bf16x8 bfr[2][2];
#pragma unroll
    for (int c = 0; c < 2; ++c)
#pragma unroll
        for (int nt = 0; nt < 2; ++nt)
            bfr[c][nt] = *(const bf16x8*)&sXT[wave][nt * 16 + l16][c * 32 + quad * 8];

    f32x4 acc[4][2];
#pragma unroll
    for (int mt = 0; mt < 4; ++mt)
#pragma unroll
        for (int nt = 0; nt < 2; ++nt) acc[mt][nt] = (f32x4){0.f, 0.f, 0.f, 0.f};

#pragma unroll
    for (int mt = 0; mt < 4; ++mt)
#pragma unroll
        for (int c = 0; c < 2; ++c) {
            bf16x8 afr = *(const bf16x8*)&sW[(mt * 16 + l16) * WS + c * 32 + quad * 8];
#pragma unroll
            for (int nt = 0; nt < 2; ++nt)
                acc[mt][nt] = __builtin_amdgcn_mfma_f32_16x16x32_bf16(afr, bfr[c][nt], acc[mt][nt], 0, 0, 0);
        }

    epi_res_mn_ln(acc, bias, Xin, Xout, gamma, lnw, lnb, Aout, tok, l16, quad, true);
}

// ---------------- fused Q/K/V GEMM -> bf16 outputs ----------------
__global__ __launch_bounds__(256, 3) void gemm_qkv_kernel(
    const float* __restrict__ X,
    const unsigned short* __restrict__ Wqh, const unsigned short* __restrict__ Wkh,
    const unsigned short* __restrict__ Wvh,
    const float* __restrict__ bq, const float* __restrict__ bk, const float* __restrict__ bv,
    unsigned short* __restrict__ Q, unsigned short* __restrict__ K, unsigned short* __restrict__ V) {
    constexpr int WS = 64 + 8;
    __shared__ short sW[3 * 64 * WS];
    __shared__ short sXT[4][32][WS];

    const int tid = threadIdx.x, wave = tid >> 6, lane = tid & 63;
    const int l16 = lane & 15, quad = lane >> 4;
    const int tok = blockIdx.x * 4 + wave;

    const unsigned short* Wp[3] = {Wqh, Wkh, Wvh};
#pragma unroll
    for (int w = 0; w < 3; ++w)
        for (int j = tid * 8; j < 64 * 64; j += 2048) {
            int o = j >> 6, i = j & 63;
            *(bf16x8*)&sW[w * 64 * WS + o * WS + i] = *(const bf16x8*)(Wp[w] + j);
        }
    {
        const int g4 = (lane & 7) * 4;
        const int i0 = (lane >> 3) * 8;
        const float* xp = X + (size_t)tok * kDG;
#pragma unroll
        for (int half = 0; half < 2; ++half) {
            float4 vr[4];
#pragma unroll
            for (int r = 0; r < 4; ++r)
                vr[r] = *(const float4*)(xp + (i0 + half * 4 + r) * kG + g4);
#pragma unroll
            for (int gg = 0; gg < 4; ++gg)
                *(short4*)&sXT[wave][g4 + gg][i0 + half * 4] =
                    make_short4(f2bf((&vr[0].x)[gg]), f2bf((&vr[1].x)[gg]),
                                f2bf((&vr[2].x)[gg]), f2bf((&vr[3].x)[gg]));
        }
    }
    __syncthreads();

    bf16x8 bfr[2][2];
#pragma unroll
    for (int c = 0; c < 2; ++c)
#pragma unroll
        for (int nt = 0; nt < 2; ++nt)
            bfr[c][nt] = *(const bf16x8*)&sXT[wave][nt * 16 + l16][c * 32 + quad * 8];

    f32x4 acc[3][4][2];
#pragma unroll
    for (int w = 0; w < 3; ++w)
#pragma unroll
        for (int mt = 0; mt < 4; ++mt)
#pragma unroll
            for (int nt = 0; nt < 2; ++nt) acc[w][mt][nt] = (f32x4){0.f, 0.f, 0.f, 0.f};

#pragma unroll
    for (int w = 0; w < 3; ++w)
#pragma unroll
        for (int mt = 0; mt < 4; ++mt)
#pragma unroll
            for (int c = 0; c < 2; ++c) {
                bf16x8 afr = *(const bf16x8*)&sW[w * 64 * WS + (mt * 16 + l16) * WS + c * 32 + quad * 8];
#pragma unroll
                for (int nt = 0; nt < 2; ++nt)
                    acc[w][mt][nt] = __builtin_amdgcn_mfma_f32_16x16x32_bf16(afr, bfr[c][nt], acc[w][mt][nt], 0, 0, 0);
            }

    unsigned short* Op[3] = {Q, K, V};
    const float* Bp[3] = {bq, bk, bv};
#pragma unroll
    for (int w = 0; w < 3; ++w) {
        unsigned short* op = Op[w] + (size_t)tok * kDG;
#pragma unroll
        for (int mt = 0; mt < 4; ++mt)
#pragma unroll
            for (int nt = 0; nt < 2; ++nt) {
                int g = nt * 16 + l16;
#pragma unroll
                for (int r = 0; r < 4; ++r) {
                    int o = mt * 16 + quad * 4 + r;
                    op[o * kG + g] = (unsigned short)f2bf(acc[w][mt][nt][r] + Bp[w][o * kG + g]);
                }
            }
    }
}

// ---------------- MLP2 GEMM with fused residual+mn+(LN1 next) epilogue -----
template<bool DO_LN>
__global__ __launch_bounds__(256, 3) void mlp2_fused_kernel(
    const unsigned short* __restrict__ Mb,  // [t][32][256] bf16
    const unsigned short* __restrict__ W2h, const float* __restrict__ b2,
    float* __restrict__ X, const float* __restrict__ gamma,
    const float* __restrict__ lnw, const float* __restrict__ lnb,
    float* __restrict__ Aout) {
    constexpr int WS = 256 + 8;
    __shared__ short sW[64 * WS];
    const int tid = threadIdx.x, wave = tid >> 6, lane = tid & 63;
    const int l16 = lane & 15, quad = lane >> 4;
    const int tok = blockIdx.x * 4 + wave;

    for (int j = tid * 8; j < 64 * 256; j += 2048) {
        int o = j >> 8, i = j & 255;
        *(bf16x8*)&sW[o * WS + i] = *(const bf16x8*)(W2h + j);
    }
    __syncthreads();

    f32x4 acc[4][2];
#pragma unroll
    for (int mt = 0; mt < 4; ++mt)
#pragma unroll
        for (int nt = 0; nt < 2; ++nt) acc[mt][nt] = (f32x4){0.f, 0.f, 0.f, 0.f};

    const unsigned short* mp = Mb + (size_t)tok * kG * kE;
#pragma unroll
    for (int c = 0; c < 8; ++c) {
        bf16x8 bfr[2];
#pragma unroll
        for (int nt = 0; nt < 2; ++nt)
            bfr[nt] = *(const bf16x8*)&mp[(nt * 16 + l16) * kE + c * 32 + quad * 8];
#pragma unroll
        for (int mt = 0; mt < 4; ++mt) {
            bf16x8 afr = *(const bf16x8*)&sW[(mt * 16 + l16) * WS + c * 32 + quad * 8];
#pragma unroll
            for (int nt = 0; nt < 2; ++nt)
                acc[mt][nt] = __builtin_amdgcn_mfma_f32_16x16x32_bf16(afr, bfr[nt], acc[mt][nt], 0, 0, 0);
        }
    }

    epi_res_mn_ln(acc, b2, X, X, gamma, lnw, lnb, Aout, tok, l16, quad, DO_LN);
}

// ---------------- MFMA attention: register prefetch + LDS double-buffer ----
// 1 block/CU -> barrier drains are the cost; double-buffered sKV halves the
// barrier count (~33 -> ~16) and overlaps global loads with MFMA.
constexpr int QSTR = 264;
constexpr int VSTR = 40;

__global__ __launch_bounds__(256) void attn_mfma_kernel(const unsigned short* __restrict__ Q,
                                                        const unsigned short* __restrict__ K,
                                                        const unsigned short* __restrict__ V,
                                                        float* __restrict__ O) {
    __shared__ short sQ[64 * QSTR];          // Q tile, later P
    __shared__ short sKV[2][256 * VSTR];     // double buffer: K tiles (32xQSTR) / V^T (256xVSTR)

    const int qt = blockIdx.x, h = blockIdx.y, b = blockIdx.z;
    const int tid = threadIdx.x;
    const int wave = tid >> 6, lane = tid & 63;
    const int l16 = lane & 15, quad = lane >> 4;

    const size_t bh = (size_t)b * kS * kDG + (size_t)h * kHD;

    // stage Q tile + K tile 0 (buf 0) cooperatively, one barrier
#pragma unroll
    for (int it = 0; it < 8; ++it) {
        int j = it * 2048 + tid * 8;
        int row = j >> 8, col = j & 255;
        *(bf16x8*)&sQ[row * QSTR + col] =
            *(const bf16x8*)(Q + bh + (size_t)(qt * 64 + row) * kDG + col);
    }
#pragma unroll
    for (int it = 0; it < 4; ++it) {
        int j = it * 2048 + tid * 8;
        int row = j >> 8, col = j & 255;
        *(bf16x8*)&sKV[0][row * QSTR + col] =
            *(const bf16x8*)(K + bh + (size_t)row * kDG + col);
    }
    __syncthreads();

    bf16x8 afrag[8];
    {
        int row = wave * 16 + l16;   // wave reads only its own 16 rows of sQ
#pragma unroll
        for (int c = 0; c < 8; ++c)
            afrag[c] = *(const bf16x8*)&sQ[row * QSTR + c * 32 + quad * 8];
    }

    f32x4 acc[16];
#pragma unroll
    for (int i = 0; i < 16; ++i) acc[i] = (f32x4){0.f, 0.f, 0.f, 0.f};

    for (int kt = 0; kt < 8; ++kt) {
        bf16x8 kpre[4];
        if (kt < 7) {
#pragma unroll
            for (int it = 0; it < 4; ++it) {
                int j = it * 2048 + tid * 8;
                int row = j >> 8, col = j & 255;
                kpre[it] = *(const bf16x8*)(K + bh + (size_t)((kt + 1) * 32 + row) * kDG + col);
            }
        }
        const short* kb = sKV[kt & 1];
#pragma unroll
        for (int nt = 0; nt < 2; ++nt) {
            int key = nt * 16 + l16;
            f32x4 a = acc[kt * 2 + nt];
#pragma unroll
            for (int c = 0; c < 8; ++c) {
                bf16x8 bfrag = *(const bf16x8*)&kb[key * QSTR + c * 32 + quad * 8];
                a = __builtin_amdgcn_mfma_f32_16x16x32_bf16(afrag[c], bfrag, a, 0, 0, 0);
            }
            acc[kt * 2 + nt] = a;
        }
        if (kt < 7) {
            short* nb = sKV[(kt + 1) & 1];
#pragma unroll
            for (int it = 0; it < 4; ++it) {
                int j = it * 2048 + tid * 8;
                int row = j >> 8, col = j & 255;
                *(bf16x8*)&nb[row * QSTR + col] = kpre[it];
            }
            __syncthreads();
        }
    }

    // softmax over 256 keys (rows = quad*4 + r)
    float inv[4];
#pragma unroll
    for (int r = 0; r < 4; ++r) {
        float m = -1e30f;
#pragma unroll
        for (int t = 0; t < 16; ++t) m = fmaxf(m, acc[t][r]);
#pragma unroll
        for (int off = 1; off < 16; off <<= 1) m = fmaxf(m, __shfl_xor(m, off, 16));
        float s = 0.f;
#pragma unroll
        for (int t = 0; t < 16; ++t) {
            float p = __expf((acc[t][r] - m) * 0.0625f);
            acc[t][r] = p; s += p;
        }
#pragma unroll
        for (int off = 1; off < 16; off <<= 1) s += __shfl_xor(s, off, 16);
        inv[r] = 1.f / s;
    }

    // P (bf16) into sQ — each wave writes/reads only its own 16 rows
#pragma unroll
    for (int t = 0; t < 16; ++t)
#pragma unroll
        for (int r = 0; r < 4; ++r)
            sQ[(wave * 16 + quad * 4 + r) * QSTR + t * 16 + l16] = f2bf(acc[t][r]);

    // V^T tile 0 into buf 0 (last read of buf0 was kt=6, barrier-protected)
    {
        int kb = tid >> 5;
#pragma unroll
        for (int it = 0; it < 2; ++it) {
            int db = (tid & 31) + it * 32;
            short4 vr[4];
#pragma unroll
            for (int r = 0; r < 4; ++r)
                vr[r] = *(const short4*)(V + bh + (size_t)(kb * 4 + r) * kDG + db * 4);
#pragma unroll
            for (int i = 0; i < 4; ++i) {
                short4 p = make_short4((&vr[0].x)[i], (&vr[1].x)[i],
                                       (&vr[2].x)[i], (&vr[3].x)[i]);
                *(short4*)&sKV[0][(db * 4 + i) * VSTR + kb * 4] = p;
            }
        }
    }
    __syncthreads();

    f32x4 oacc[16];
#pragma unroll
    for (int i = 0; i < 16; ++i) oacc[i] = (f32x4){0.f, 0.f, 0.f, 0.f};

    for (int vt = 0; vt < 8; ++vt) {
        short4 vpre[8];
        if (vt < 7) {
            int kb = tid >> 5;
#pragma unroll
            for (int it = 0; it < 2; ++it) {
                int db = (tid & 31) + it * 32;
#pragma unroll
                for (int r = 0; r < 4; ++r)
                    vpre[it * 4 + r] = *(const short4*)(V + bh + (size_t)((vt + 1) * 32 + kb * 4 + r) * kDG + db * 4);
            }
        }
        const short* vb = sKV[vt & 1];
        bf16x8 pfrag = *(const bf16x8*)&sQ[(wave * 16 + l16) * QSTR + vt * 32 + quad * 8];
#pragma unroll
        for (int dt = 0; dt < 16; ++dt) {
            bf16x8 vfrag = *(const bf16x8*)&vb[(dt * 16 + l16) * VSTR + quad * 8];
            oacc[dt] = __builtin_amdgcn_mfma_f32_16x16x32_bf16(pfrag, vfrag, oacc[dt], 0, 0, 0);
        }
        if (vt < 7) {
            short* nb = sKV[(vt + 1) & 1];
            int kb = tid >> 5;
#pragma unroll
            for (int it = 0; it < 2; ++it) {
                int db = (tid & 31) + it * 32;
#pragma unroll
                for (int i = 0; i < 4; ++i) {
                    short4 p = make_short4((&vpre[it * 4 + 0].x)[i], (&vpre[it * 4 + 1].x)[i],
                                           (&vpre[it * 4 + 2].x)[i], (&vpre[it * 4 + 3].x)[i]);
                    *(short4*)&nb[(db * 4 + i) * VSTR + kb * 4] = p;
                }
            }
            __syncthreads();
        }
    }

    {
        int qrow = qt * 64 + wave * 16 + quad * 4;
#pragma unroll
        for (int dt = 0; dt < 16; ++dt)
#pragma unroll
            for (int r = 0; r < 4; ++r)
                O[bh + (size_t)(qrow + r) * kDG + dt * 16 + l16] = oacc[dt][r] * inv[r];
    }
}

// ---------------- in-thread geometric product with compile-time signs -------
constexpr int pc_ce(unsigned v) { int c = 0; while (v) { c += v & 1; v >>= 1; } return c; }
constexpr unsigned gp_mask_ce(int a) {
    unsigned m = 0;
    for (int c = 0; c < 32; ++c) {
        int b = a ^ c;
        int s = (a & b) >> 4;
        for (int t = a >> 1; t; t >>= 1) s += pc_ce(t & b);
        if (s & 1) m |= (1u << c);
    }
    return m;
}

template<int A>
__device__ __forceinline__ void gp_term(const float* x, const float* y, float* acc) {
    constexpr unsigned m = gp_mask_ce(A);
    const float xa = x[A], nxa = -xa;
#pragma unroll
    for (int c = 0; c < 32; ++c)
        acc[c] = fmaf(((m >> c) & 1u) ? nxa : xa, y[A ^ c], acc[c]);
}

__device__ __forceinline__ void gp_mn_t(const float* x, const float* y, float* out) {
    float acc[32];
#pragma unroll
    for (int c = 0; c < 32; ++c) acc[c] = 0.f;
    gp_term<0>(x, y, acc);  gp_term<1>(x, y, acc);  gp_term<2>(x, y, acc);  gp_term<3>(x, y, acc);
    gp_term<4>(x, y, acc);  gp_term<5>(x, y, acc);  gp_term<6>(x, y, acc);  gp_term<7>(x, y, acc);
    gp_term<8>(x, y, acc);  gp_term<9>(x, y, acc);  gp_term<10>(x, y, acc); gp_term<11>(x, y, acc);
    gp_term<12>(x, y, acc); gp_term<13>(x, y, acc); gp_term<14>(x, y, acc); gp_term<15>(x, y, acc);
    gp_term<16>(x, y, acc); gp_term<17>(x, y, acc); gp_term<18>(x, y, acc); gp_term<19>(x, y, acc);
    gp_term<20>(x, y, acc); gp_term<21>(x, y, acc); gp_term<22>(x, y, acc); gp_term<23>(x, y, acc);
    gp_term<24>(x, y, acc); gp_term<25>(x, y, acc); gp_term<26>(x, y, acc); gp_term<27>(x, y, acc);
    gp_term<28>(x, y, acc); gp_term<29>(x, y, acc); gp_term<30>(x, y, acc); gp_term<31>(x, y, acc);
    float ss = 0.f;
#pragma unroll
    for (int c = 0; c < 32; ++c) ss = fmaf(acc[c], acc[c], ss);
    float r = 1.f / (sqrtf(ss) + 1e-6f);
#pragma unroll
    for (int c = 0; c < 32; ++c) out[c] = acc[c] * r;
}

__device__ __forceinline__ void leaf_load(const float* base, float* v) {
#pragma unroll
    for (int i = 0; i < 8; ++i) {
        const float4 f = *(const float4*)(base + i * 4);
        v[i * 4 + 0] = 0.5f * f.x; v[i * 4 + 1] = 0.5f * f.y;
        v[i * 4 + 2] = 0.5f * f.z; v[i * 4 + 3] = 0.5f * f.w;
    }
    v[0] += 1.f;
    float ss = 0.f;
#pragma unroll
    for (int c = 0; c < 32; ++c) ss = fmaf(v[c], v[c], ss);
    float r = 1.f / (sqrtf(ss) + 1e-6f);
#pragma unroll
    for (int c = 0; c < 32; ++c) v[c] *= r;
}

// ---------------- scan: wave per sequence, rotor per thread -----------------
__global__ __launch_bounds__(256) void scanreg_kernel(const float* __restrict__ DT,
                                                      float* __restrict__ pooled) {
    const int wave = threadIdx.x >> 6, lane = threadIdx.x & 63;
    const int seq = blockIdx.x * 4 + wave;
    const float* base = DT + ((size_t)seq * kS + lane * 4) * kG;

    float R[32], Y[32], P[32], Xa[32], Yb[32];

    leaf_load(base, R);
    for (int j = 1; j < 4; ++j) {
        leaf_load(base + j * kG, Y);
        gp_mn_t(Y, R, R);
    }

    for (int step = 1; step < 64; step <<= 1) {
        const bool up = lane & step;
#pragma unroll
        for (int c = 0; c < 32; ++c) P[c] = __shfl_xor(R[c], step, 64);
#pragma unroll
        for (int c = 0; c < 32; ++c) {
            Xa[c] = up ? R[c] : P[c];
            Yb[c] = up ? P[c] : R[c];
        }
        gp_mn_t(Xa, Yb, R);
    }

    if (lane == 0) {
        float* op = pooled + (size_t)seq * kG;
#pragma unroll
        for (int i = 0; i < 8; ++i)
            *(float4*)(op + i * 4) = make_float4(R[i * 4], R[i * 4 + 1], R[i * 4 + 2], R[i * 4 + 3]);
    }
}

// ---------------- classifier ----------------
__global__ __launch_bounds__(256) void cls2_kernel(const float* __restrict__ P,
                                                   const float* __restrict__ Wc,
                                                   const float* __restrict__ bc,
                                                   float* __restrict__ out) {
    __shared__ float sp[kB * kDG];
    const int tid = threadIdx.x, wave = tid >> 6, lane = tid & 63;
    for (int j = tid * 4; j < kB * kDG; j += 1024)
        *(float4*)&sp[j] = *(const float4*)(P + j);
    __syncthreads();

    const int c = blockIdx.x * 4 + wave;
    const float* w = Wc + (size_t)c * kDG;
    float acc[kB];
#pragma unroll
    for (int b = 0; b < kB; ++b) acc[b] = 0.f;
#pragma unroll
    for (int cc = 0; cc < 8; ++cc) {
        const float4 w4 = *(const float4*)(w + cc * 256 + lane * 4);
#pragma unroll
        for (int b = 0; b < kB; ++b) {
            const float4 p4 = *(const float4*)&sp[b * kDG + cc * 256 + lane * 4];
            acc[b] += w4.x * p4.x + w4.y * p4.y + w4.z * p4.z + w4.w * p4.w;
        }
    }
#pragma unroll
    for (int b = 0; b < kB; ++b)
#pragma unroll
        for (int off = 32; off > 0; off >>= 1) acc[b] += __shfl_xor(acc[b], off, 64);
    if (lane == 0) {
        float bias = bc[c];
#pragma unroll
        for (int b = 0; b < kB; ++b) out[b * kNC + c] = acc[b] + bias;
    }
}

extern "C" void kernel_launch(void* const* d_in, const int* in_sizes, int n_in,
                              void* d_out, int out_size, void* d_ws, size_t ws_size,
                              hipStream_t stream) {
    const float* x_in = (const float*)d_in[0];
    const float* Wq   = (const float*)d_in[1];
    const float* bq   = (const float*)d_in[2];
    const float* Wk   = (const float*)d_in[3];
    const float* bk   = (const float*)d_in[4];
    const float* Wv   = (const float*)d_in[5];
    const float* bv   = (const float*)d_in[6];
    const float* Wo   = (const float*)d_in[7];
    const float* bo   = (const float*)d_in[8];
    const float* ln1w = (const float*)d_in[9];
    const float* ln1b = (const float*)d_in[10];
    const float* ln2w = (const float*)d_in[11];
    const float* ln2b = (const float*)d_in[12];
    const float* gm1  = (const float*)d_in[13];
    const float* gm2  = (const float*)d_in[14];
    const float* W1   = (const float*)d_in[15];
    const float* b1   = (const float*)d_in[16];
    const float* W2   = (const float*)d_in[17];
    const float* b2   = (const float*)d_in[18];
    const float* Wr   = (const float*)d_in[19];
    const float* br   = (const float*)d_in[20];
    const float* Wc   = (const float*)d_in[21];
    const float* bc   = (const float*)d_in[22];

    const size_t NEL = (size_t)kT * kDG;
    float* F  = (float*)d_ws;
    float* X  = F;                                   // region 0
    float* A  = F + NEL;                             // region 1 (LN out / attn O / DT)
    unsigned short* Qh = (unsigned short*)(F + 2 * NEL);
    unsigned short* Kh = (unsigned short*)(F + 3 * NEL);
    unsigned short* Vh = (unsigned short*)(F + 4 * NEL);
    unsigned short* Mb = (unsigned short*)(F + 3 * NEL);   // spans regions 3-4
    unsigned short* Wb = (unsigned short*)(F + 5 * NEL);   // bf16 weights (384 KB)
    float* pooled = F + 2 * NEL;
    float* DT = A;

    // bf16 weight copies: [Wq|Wk|Wv|Wo: 16384 each][W1: 65536][W2: 65536]
    cvtw_kernel<<<192, 256, 0, stream>>>(Wq, Wk, Wv, Wo, W1, W2, Wb);
    unsigned short* Wqh = Wb;
    unsigned short* Wkh = Wb + 16384;
    unsigned short* Wvh = Wb + 32768;
    unsigned short* Woh = Wb + 49152;
    unsigned short* W1h = Wb + 65536;
    unsigned short* W2h = Wb + 131072;

    ln_kernel<<<kT, 256, 0, stream>>>(x_in, ln1w, ln1b, A);

    for (int l = 0; l < 4; l++) {
        gemm_qkv_kernel<<<kT / 4, 256, 0, stream>>>(A,
            Wqh + l * 4096, Wkh + l * 4096, Wvh + l * 4096,
            bq + l * kDG, bk + l * kDG, bv + l * kDG, Qh, Kh, Vh);
        attn_mfma_kernel<<<dim3(4, kNH, kB), 256, 0, stream>>>(Qh, Kh, Vh, A);
        gemmWo_fused_kernel<<<kT / 4, 256, 0, stream>>>(A, Woh + l * 4096, bo + l * kDG,
            l == 0 ? x_in : X, gm1 + l * kDG, ln2w + l * kDG, ln2b + l * kDG, X, A);
        mlp1_kernel<<<kT / 4, 256, 0, stream>>>(A, W1h + l * 16384, b1 + l * kE * kG, Mb);
        if (l < 3)
            mlp2_fused_kernel<true><<<kT / 4, 256, 0, stream>>>(Mb, W2h + l * 16384, b2 + l * kDG,
                X, gm2 + l * kDG, ln1w + (l + 1) * kDG, ln1b + (l + 1) * kDG, A);
        else
            mlp2_fused_kernel<false><<<kT / 4, 256, 0, stream>>>(Mb, W2h + l * 16384, b2 + l * kDG,
                X, gm2 + l * kDG, nullptr, nullptr, nullptr);
    }

    // delta (fp32, transposed) -> register-resident reduction -> classifier
    vlinT_kernel<<<kT, 256, 0, stream>>>(X, Wr, br, DT);
    scanreg_kernel<<<kB * kD / 4, 256, 0, stream>>>(DT, pooled);
    cls2_kernel<<<kNC / 4, 256, 0, stream>>>(pooled, Wc, bc, (float*)d_out);
}